// Round 2
// baseline (549.889 us; speedup 1.0000x reference)
//
#include <hip/hip_runtime.h>
#include <math.h>

#define NN 588
#define EE 9408
#define HD 64
#define NTHR 768
#define NW (NTHR/64)
#define NEGS 0.01f
#define THRESHV 0.999f

__device__ __forceinline__ float lrelu(float v){ return v >= 0.f ? v : NEGS*v; }
__device__ __forceinline__ float sigm(float v){ return 1.f/(1.f+expf(-v)); }
__device__ __forceinline__ float rdlane(float v, int l){
  return __int_as_float(__builtin_amdgcn_readlane(__float_as_int(v), l));
}
__device__ __forceinline__ float wredsum(float v){
  v += __shfl_down(v,32); v += __shfl_down(v,16); v += __shfl_down(v,8);
  v += __shfl_down(v,4);  v += __shfl_down(v,2);  v += __shfl_down(v,1);
  return v;  // valid on lane 0
}

// inp[n] = lrelu(b3 + sum_{e:dst=n} y[src_e]);  gx[r] = bi[r] + dot(wi[r,:], inp)
__device__ __forceinline__ void gx_phase(const float* wi, const float* bi, float b3v,
                                         const int* offL, const int* eidxL,
                                         const float* yL, float* inpL, float* gxL,
                                         int tid, int lane, int w) {
  for (int t = tid; t < NN; t += NTHR) {
    float a = 0.f;
    int e0 = offL[t], e1 = offL[t+1];
    for (int k = e0; k < e1; ++k) a += yL[eidxL[k]];
    inpL[t] = lrelu(a + b3v);
  }
  __syncthreads();
  for (int r = w*16; r < w*16 + 16; ++r) {
    float p = 0.f;
    const float* row = wi + r*NN;
    for (int c = lane; c < NN; c += 64) p += row[c]*inpL[c];
    p = wredsum(p);
    if (lane == 0) gxL[r] = p + bi[r];
  }
  __syncthreads();
}

__global__ __launch_bounds__(NTHR)
void lastgcn_kernel(const float* feat, const int* src, const int* dst,
                    const float* W1, const float* b1, const float* W2, const float* b2,
                    const float* W3, const float* b3, const float* W5, const float* b5,
                    const float* wi, const float* wh, const float* bi, const float* bh,
                    const float* w_end, const float* b_end, const int* capp,
                    float* out, float* x0g, float* x1g) {
  const int tid  = threadIdx.x;
  const int lane = tid & 63;
  const int w    = tid >> 6;
  const int grp  = lane >> 4;
  const int l16  = lane & 15;

  __shared__ int    eidxL[EE];      // 37632 B
  __shared__ int    offL[NN+1];
  __shared__ int    curL[NN];       // deg, then cursor
  __shared__ float4 f4L[NN];        // feature sums
  __shared__ float  yL[NN];
  __shared__ float  inpL[NN];
  __shared__ float  gxL[192];
  __shared__ float  ghL[192];
  __shared__ float  stateL[64];
  __shared__ float  aggS[NW*64];
  __shared__ int    wsumL[NW];
  __shared__ float  sScal[3];       // s, fprob, counter
  __shared__ int    sStop;

  // ---- CSR build (all in LDS) ----
  for (int t = tid; t < NN; t += NTHR) curL[t] = 0;
  __syncthreads();
  for (int e = tid; e < EE; e += NTHR) atomicAdd(&curL[dst[e]], 1);
  __syncthreads();
  // exclusive prefix over 588 degrees
  {
    int myv = (tid < NN) ? curL[tid] : 0;
    int inc = myv;
    for (int o = 1; o < 64; o <<= 1) { int u = __shfl_up(inc, o); if (lane >= o) inc += u; }
    if (lane == 63) wsumL[w] = inc;
    __syncthreads();
    if (w == 0) {
      int s0 = (lane < NW) ? wsumL[lane] : 0;
      int is = s0;
      for (int o = 1; o < NW; o <<= 1) { int u = __shfl_up(is, o); if (lane >= o) is += u; }
      if (lane < NW) wsumL[lane] = is - s0;  // exclusive wave prefix
    }
    __syncthreads();
    if (tid < NN) { int ex = wsumL[w] + inc - myv; offL[tid] = ex; curL[tid] = ex; }
    if (tid == 0) offL[NN] = EE;
    __syncthreads();
  }
  for (int e = tid; e < EE; e += NTHR) {
    int p = atomicAdd(&curL[dst[e]], 1);
    eidxL[p] = src[e];
  }
  __syncthreads();

  // ---- conv1: feature sums, then x0 = lrelu(agg @ W1 + b1), y0 = x0 @ W3 ----
  for (int t = tid; t < NN; t += NTHR) {
    float fx=0.f, fy=0.f, fz=0.f, fw=0.f;
    int e0 = offL[t], e1 = offL[t+1];
    for (int k = e0; k < e1; ++k) {
      const float4 fv = *(const float4*)(feat + eidxL[k]*4);
      fx += fv.x; fy += fv.y; fz += fv.z; fw += fv.w;
    }
    f4L[t] = make_float4(fx, fy, fz, fw);
  }
  __syncthreads();
  const float W3r = W3[lane];
  for (int n = w; n < NN; n += NW) {
    float4 f = f4L[n];
    float v = b1[lane] + f.x*W1[lane] + f.y*W1[64+lane] + f.z*W1[128+lane] + f.w*W1[192+lane];
    v = lrelu(v);
    x0g[(size_t)n*HD + lane] = v;
    float yv = wredsum(v * W3r);
    if (lane == 0) yL[n] = yv;
  }
  __syncthreads();

  const float b3v = b3[0];
  // ---- initial gx + GRU init ----
  gx_phase(wi, bi, b3v, offL, eidxL, yL, inpL, gxL, tid, lane, w);
  if (w == 0) {
    int j = lane;
    float r  = sigm(gxL[j]      + bh[j]);
    float z  = sigm(gxL[64+j]   + bh[64+j]);
    float n2 = tanhf(gxL[128+j] + r*bh[128+j]);
    float st = (1.f - z)*n2;            // h0 = 0
    stateL[j] = st;
    float t2 = wredsum(st * w_end[j]);
    if (j == 0) {
      float pr = sigm(t2 + b_end[0]);
      sScal[0] = pr; sScal[1] = pr; sScal[2] = 0.f;
      sStop = (pr >= THRESHV) ? 1 : 0;
    }
  }
  __syncthreads();
  // gh = bh + wh @ state (frozen state, computed once)
  for (int r = w*16; r < w*16 + 16; ++r) {
    float p = wredsum(wh[r*64 + lane] * stateL[lane]);
    if (lane == 0) ghL[r] = p + bh[r];
  }
  __syncthreads();

  // ---- main loop ----
  const int cap = capp[0];
  float* xc = x0g;
  float* xn = x1g;
  for (int it = 0; it < cap; ++it) {
    if (sStop) break;   // uniform

    // conv2: xn = lrelu(segsum(xc) @ W2 + b2); y = xn @ W3
    {
      float w2r[64];
      #pragma unroll
      for (int k = 0; k < 64; ++k) w2r[k] = W2[k*64 + lane];
      const float b2r = b2[lane];
      for (int n = w; n < NN; n += NW) {
        int e0 = offL[n], e1 = offL[n+1];
        float aq[4] = {0.f, 0.f, 0.f, 0.f};
        for (int cb = e0; cb < e1; cb += 64) {
          int rem = e1 - cb; rem = rem > 64 ? 64 : rem;
          int myidx = (lane < rem) ? eidxL[cb + lane] : 0;
          for (int t4 = 0; t4 < rem; t4 += 4) {
            int sub = t4 + grp;
            int sidx = __shfl(myidx, sub);
            if (sub < rem) {
              const float4 xv = *(const float4*)(xc + (size_t)sidx*HD + l16*4);
              aq[0] += xv.x; aq[1] += xv.y; aq[2] += xv.z; aq[3] += xv.w;
            }
          }
        }
        #pragma unroll
        for (int c = 0; c < 4; ++c) {
          aq[c] += __shfl_down(aq[c], 32);
          aq[c] += __shfl_down(aq[c], 16);
        }
        // lanes 0-15 hold agg quads; broadcast via readlane, 2 FMA chains
        float oA = 0.f, oB = 0.f;
        #pragma unroll
        for (int k = 0; k < 64; k += 2) {
          oA = fmaf(rdlane(aq[k & 3],       k >> 2),       w2r[k],   oA);
          oB = fmaf(rdlane(aq[(k+1) & 3],  (k+1) >> 2),    w2r[k+1], oB);
        }
        float v = lrelu(b2r + oA + oB);
        xn[(size_t)n*HD + lane] = v;
        float yv = wredsum(v * W3r);
        if (lane == 0) yL[n] = yv;
      }
    }
    __syncthreads();

    gx_phase(wi, bi, b3v, offL, eidxL, yL, inpL, gxL, tid, lane, w);

    if (w == 0) {
      int j = lane;
      float r  = sigm(gxL[j]      + ghL[j]);
      float z  = sigm(gxL[64+j]   + ghL[64+j]);
      float n2 = tanhf(gxL[128+j] + r*ghL[128+j]);
      float st = (1.f - z)*n2 + z*stateL[j];   // frozen state
      float t2 = wredsum(st * w_end[j]);
      if (j == 0) {
        float pr = sigm(t2 + b_end[0]);
        float s = sScal[0] + pr;
        sScal[0] = s; sScal[1] = pr; sScal[2] += 1.f;
        sStop = (s >= THRESHV) ? 1 : 0;
      }
    }
    __syncthreads();

    float* tmp = xc; xc = xn; xn = tmp;
  }

  // ---- final conv: out = segsum(x_last) @ W5 + b5 ----
  for (int n = w; n < NN; n += NW) {
    int e0 = offL[n], e1 = offL[n+1];
    float aq[4] = {0.f, 0.f, 0.f, 0.f};
    for (int cb = e0; cb < e1; cb += 64) {
      int rem = e1 - cb; rem = rem > 64 ? 64 : rem;
      int myidx = (lane < rem) ? eidxL[cb + lane] : 0;
      for (int t4 = 0; t4 < rem; t4 += 4) {
        int sub = t4 + grp;
        int sidx = __shfl(myidx, sub);
        if (sub < rem) {
          const float4 xv = *(const float4*)(xc + (size_t)sidx*HD + l16*4);
          aq[0] += xv.x; aq[1] += xv.y; aq[2] += xv.z; aq[3] += xv.w;
        }
      }
    }
    #pragma unroll
    for (int c = 0; c < 4; ++c) {
      aq[c] += __shfl_down(aq[c], 32);
      aq[c] += __shfl_down(aq[c], 16);
    }
    if (lane < 16) *(float4*)&aggS[w*64 + lane*4] = make_float4(aq[0], aq[1], aq[2], aq[3]);
    float ak = aggS[w*64 + lane];       // lane k holds agg[k]
    float p0 = wredsum(ak * W5[lane*3 + 0]);
    float p1 = wredsum(ak * W5[lane*3 + 1]);
    float p2 = wredsum(ak * W5[lane*3 + 2]);
    if (lane == 0) {
      out[n*3 + 0] = p0 + b5[0];
      out[n*3 + 1] = p1 + b5[1];
      out[n*3 + 2] = p2 + b5[2];
    }
  }
  if (tid == 0) {
    out[NN*3]     = sScal[2];  // counter (as float)
    out[NN*3 + 1] = sScal[1];  // fprob
  }
}

extern "C" void kernel_launch(void* const* d_in, const int* in_sizes, int n_in,
                              void* d_out, int out_size, void* d_ws, size_t ws_size,
                              hipStream_t stream) {
  const float* feat  = (const float*)d_in[0];
  const int*   src   = (const int*)d_in[1];
  const int*   dst   = (const int*)d_in[2];
  const float* W1    = (const float*)d_in[3];
  const float* b1    = (const float*)d_in[4];
  const float* W2    = (const float*)d_in[5];
  const float* b2    = (const float*)d_in[6];
  const float* W3    = (const float*)d_in[7];
  const float* b3    = (const float*)d_in[8];
  const float* W5    = (const float*)d_in[9];
  const float* b5    = (const float*)d_in[10];
  const float* wi    = (const float*)d_in[11];
  const float* wh    = (const float*)d_in[12];
  const float* bi    = (const float*)d_in[13];
  const float* bh    = (const float*)d_in[14];
  const float* w_end = (const float*)d_in[15];
  const float* b_end = (const float*)d_in[16];
  const int*   capp  = (const int*)d_in[17];

  float* out = (float*)d_out;
  float* x0g = (float*)d_ws;
  float* x1g = x0g + (size_t)NN*HD;

  lastgcn_kernel<<<dim3(1), dim3(NTHR), 0, stream>>>(
      feat, src, dst, W1, b1, W2, b2, W3, b3, W5, b5,
      wi, wh, bi, bh, w_end, b_end, capp, out, x0g, x1g);
}

// Round 3
// 480.693 us; speedup vs baseline: 1.1439x; 1.1439x over previous
//
#include <hip/hip_runtime.h>
#include <math.h>

#define NN 588
#define EE 9408
#define HD 64
#define NTHR 768
#define NW (NTHR/64)
#define NEGS 0.01f
#define THRESHV 0.999f

__device__ __forceinline__ float lrelu(float v){ return v >= 0.f ? v : NEGS*v; }
__device__ __forceinline__ float sigm(float v){ return 1.f/(1.f+expf(-v)); }
__device__ __forceinline__ float rdlane(float v, int l){
  return __int_as_float(__builtin_amdgcn_readlane(__float_as_int(v), l));
}
__device__ __forceinline__ float wredsum(float v){
  v += __shfl_down(v,32); v += __shfl_down(v,16); v += __shfl_down(v,8);
  v += __shfl_down(v,4);  v += __shfl_down(v,2);  v += __shfl_down(v,1);
  return v;  // valid on lane 0
}

__device__ __forceinline__ void sink4(float4 v){
  asm volatile("" :: "v"(v.x), "v"(v.y), "v"(v.z), "v"(v.w));
}

// Warm L2 with high MLP: batches of 8 outstanding float4 loads per lane.
// nfloats must be a multiple of 4 (all our regions are).
__device__ __forceinline__ void prefetch_region(const float* p0, int nfloats, int t, int T){
  const float4* p = (const float4*)p0;
  const int n = nfloats >> 2;
  for (int base = t; base < n; base += T*8) {
    float4 v[8];
    #pragma unroll
    for (int u = 0; u < 8; ++u) {
      int i = base + u*T; if (i >= n) i = n - 1;   // clamp: redundant loads are harmless
      v[u] = p[i];
    }
    #pragma unroll
    for (int u = 0; u < 8; ++u) sink4(v[u]);
  }
}

// inp[n] = lrelu(b3 + sum_{e:dst=n} y[src_e]);  gx[r] = bi[r] + dot(wi[r,:], inp)
__device__ __forceinline__ void gx_phase(const float* wi, const float* bi, float b3v,
                                         const int* offL, const int* eidxL,
                                         const float* yL, float* inpL, float* gxL,
                                         int tid, int lane, int w) {
  for (int t = tid; t < NN; t += NTHR) {
    float a = 0.f;
    int e0 = offL[t], e1 = offL[t+1];
    for (int k = e0; k < e1; ++k) a += yL[eidxL[k]];
    inpL[t] = lrelu(a + b3v);
  }
  __syncthreads();
  for (int r = w*16; r < w*16 + 16; ++r) {
    const float* row = wi + r*NN;
    float p = 0.f;
    #pragma unroll
    for (int k = 0; k < 10; ++k) {          // 10*64 = 640 >= 588; masked tail
      int c = lane + k*64;
      if (c < NN) p += row[c]*inpL[c];
    }
    p = wredsum(p);
    if (lane == 0) gxL[r] = p + bi[r];
  }
  __syncthreads();
}

__global__ __launch_bounds__(NTHR)
void lastgcn_kernel(const float* feat, const int* src, const int* dst,
                    const float* W1, const float* b1, const float* W2, const float* b2,
                    const float* W3, const float* b3, const float* W5, const float* b5,
                    const float* wi, const float* wh, const float* bi, const float* bh,
                    const float* w_end, const float* b_end, const int* capp,
                    float* out, float* x0g, float* x1g) {
  const int tid  = threadIdx.x;
  const int lane = tid & 63;
  const int w    = tid >> 6;

  __shared__ int    eidxL[EE];
  __shared__ int    offL[NN+1];
  __shared__ int    curL[NN];
  __shared__ float4 f4L[NN];
  __shared__ float  yL[NN];
  __shared__ float  inpL[NN];
  __shared__ float  gxL[192];
  __shared__ float  ghL[192];
  __shared__ float  stateL[64];
  __shared__ int    wsumL[NW];
  __shared__ float  sScal[3];       // s, fprob, counter
  __shared__ int    sStop;

  // ---- split start: waves 0-3 count degrees; waves 4-11 prefetch all inputs ----
  for (int t = tid; t < NN; t += NTHR) curL[t] = 0;
  __syncthreads();
  if (w < 4) {
    for (int e = tid; e < EE; e += 256) atomicAdd(&curL[dst[e]], 1);
  } else {
    const int pt = (w-4)*64 + lane;   // 0..511
    const int PT = 512;
    prefetch_region(wi,   192*NN, pt, PT);   // 451 KB — the big one
    prefetch_region(wh,   192*64, pt, PT);
    prefetch_region(W2,   64*64,  pt, PT);
    prefetch_region(feat, NN*4,   pt, PT);
    prefetch_region(W1,   4*64,   pt, PT);
    prefetch_region(bi,   192,    pt, PT);
    prefetch_region(bh,   192,    pt, PT);
    prefetch_region(W3,   64,     pt, PT);
    prefetch_region(W5,   64*3,   pt, PT);
    prefetch_region(w_end,64,     pt, PT);
  }
  __syncthreads();

  // ---- exclusive prefix over degrees ----
  {
    int myv = (tid < NN) ? curL[tid] : 0;
    int inc = myv;
    for (int o = 1; o < 64; o <<= 1) { int u = __shfl_up(inc, o); if (lane >= o) inc += u; }
    if (lane == 63) wsumL[w] = inc;
    __syncthreads();
    if (w == 0) {
      int s0 = (lane < NW) ? wsumL[lane] : 0;
      int is = s0;
      for (int o = 1; o < NW; o <<= 1) { int u = __shfl_up(is, o); if (lane >= o) is += u; }
      if (lane < NW) wsumL[lane] = is - s0;
    }
    __syncthreads();
    if (tid < NN) { int ex = wsumL[w] + inc - myv; offL[tid] = ex; curL[tid] = ex; }
    if (tid == 0) offL[NN] = EE;
    __syncthreads();
  }
  for (int e = tid; e < EE; e += NTHR) {
    int p = atomicAdd(&curL[dst[e]], 1);
    eidxL[p] = src[e];
  }
  __syncthreads();

  // ---- conv1: feature sums, x0 = lrelu(agg @ W1 + b1), y0 = x0 @ W3 ----
  for (int t = tid; t < NN; t += NTHR) {
    float fx=0.f, fy=0.f, fz=0.f, fw=0.f;
    int e0 = offL[t], e1 = offL[t+1];
    for (int k = e0; k < e1; ++k) {
      const float4 fv = *(const float4*)(feat + eidxL[k]*4);
      fx += fv.x; fy += fv.y; fz += fv.z; fw += fv.w;
    }
    f4L[t] = make_float4(fx, fy, fz, fw);
  }
  __syncthreads();
  const float W3r = W3[lane];
  for (int n = w; n < NN; n += NW) {
    float4 f = f4L[n];
    float v = b1[lane] + f.x*W1[lane] + f.y*W1[64+lane] + f.z*W1[128+lane] + f.w*W1[192+lane];
    v = lrelu(v);
    x0g[(size_t)n*HD + lane] = v;
    float yv = wredsum(v * W3r);
    if (lane == 0) yL[n] = yv;
  }
  __syncthreads();

  const float b3v = b3[0];
  // ---- initial gx + GRU init ----
  gx_phase(wi, bi, b3v, offL, eidxL, yL, inpL, gxL, tid, lane, w);
  if (w == 0) {
    int j = lane;
    float r  = sigm(gxL[j]      + bh[j]);
    float z  = sigm(gxL[64+j]   + bh[64+j]);
    float n2 = tanhf(gxL[128+j] + r*bh[128+j]);
    float st = (1.f - z)*n2;            // h0 = 0
    stateL[j] = st;
    float t2 = wredsum(st * w_end[j]);
    if (j == 0) {
      float pr = sigm(t2 + b_end[0]);
      sScal[0] = pr; sScal[1] = pr; sScal[2] = 0.f;
      sStop = (pr >= THRESHV) ? 1 : 0;
    }
  }
  __syncthreads();
  // gh = bh + wh @ state (frozen state, computed once)
  for (int r = w*16; r < w*16 + 16; ++r) {
    float p = wredsum(wh[r*64 + lane] * stateL[lane]);
    if (lane == 0) ghL[r] = p + bh[r];
  }
  __syncthreads();

  // ---- main loop ----
  const int cap = capp[0];
  float* xc = x0g;
  float* xn = x1g;
  for (int it = 0; it < cap; ++it) {
    if (sStop) break;   // uniform

    // conv2: xn = lrelu(segsum(xc) @ W2 + b2); y = xn @ W3
    {
      float w2r[64];
      #pragma unroll
      for (int k = 0; k < 64; ++k) w2r[k] = W2[k*64 + lane];
      const float b2r = b2[lane];
      for (int n = w; n < NN; n += NW) {
        int e0 = offL[n], e1 = offL[n+1];
        float acc = 0.f;
        for (int k = e0; k < e1; k += 8) {       // batches of 8 outstanding rows
          float t[8];
          #pragma unroll
          for (int u = 0; u < 8; ++u) {
            int kk = k + u;
            t[u] = (kk < e1) ? xc[(size_t)eidxL[kk]*HD + lane] : 0.f;
          }
          #pragma unroll
          for (int u = 0; u < 8; ++u) acc += t[u];
        }
        // acc = agg[lane]; out[j] = sum_l agg[l]*W2[l][j] via 4 readlane chains
        float o0=0.f,o1=0.f,o2=0.f,o3=0.f;
        #pragma unroll
        for (int l = 0; l < 64; l += 4) {
          o0 = fmaf(rdlane(acc, l),   w2r[l],   o0);
          o1 = fmaf(rdlane(acc, l+1), w2r[l+1], o1);
          o2 = fmaf(rdlane(acc, l+2), w2r[l+2], o2);
          o3 = fmaf(rdlane(acc, l+3), w2r[l+3], o3);
        }
        float v = lrelu(b2r + (o0+o1)+(o2+o3));
        xn[(size_t)n*HD + lane] = v;
        float yv = wredsum(v * W3r);
        if (lane == 0) yL[n] = yv;
      }
    }
    __syncthreads();

    gx_phase(wi, bi, b3v, offL, eidxL, yL, inpL, gxL, tid, lane, w);

    if (w == 0) {
      int j = lane;
      float r  = sigm(gxL[j]      + ghL[j]);
      float z  = sigm(gxL[64+j]   + ghL[64+j]);
      float n2 = tanhf(gxL[128+j] + r*ghL[128+j]);
      float st = (1.f - z)*n2 + z*stateL[j];   // frozen state
      float t2 = wredsum(st * w_end[j]);
      if (j == 0) {
        float pr = sigm(t2 + b_end[0]);
        float s = sScal[0] + pr;
        sScal[0] = s; sScal[1] = pr; sScal[2] += 1.f;
        sStop = (s >= THRESHV) ? 1 : 0;
      }
    }
    __syncthreads();

    float* tmp = xc; xc = xn; xn = tmp;
  }

  // ---- final conv: out = segsum(x_last) @ W5 + b5 ----
  for (int n = w; n < NN; n += NW) {
    int e0 = offL[n], e1 = offL[n+1];
    float acc = 0.f;
    for (int k = e0; k < e1; k += 8) {
      float t[8];
      #pragma unroll
      for (int u = 0; u < 8; ++u) {
        int kk = k + u;
        t[u] = (kk < e1) ? xc[(size_t)eidxL[kk]*HD + lane] : 0.f;
      }
      #pragma unroll
      for (int u = 0; u < 8; ++u) acc += t[u];
    }
    // acc = agg[lane]
    float p0 = wredsum(acc * W5[lane*3 + 0]);
    float p1 = wredsum(acc * W5[lane*3 + 1]);
    float p2 = wredsum(acc * W5[lane*3 + 2]);
    if (lane == 0) {
      out[n*3 + 0] = p0 + b5[0];
      out[n*3 + 1] = p1 + b5[1];
      out[n*3 + 2] = p2 + b5[2];
    }
  }
  if (tid == 0) {
    out[NN*3]     = sScal[2];  // counter (as float)
    out[NN*3 + 1] = sScal[1];  // fprob
  }
}

extern "C" void kernel_launch(void* const* d_in, const int* in_sizes, int n_in,
                              void* d_out, int out_size, void* d_ws, size_t ws_size,
                              hipStream_t stream) {
  const float* feat  = (const float*)d_in[0];
  const int*   src   = (const int*)d_in[1];
  const int*   dst   = (const int*)d_in[2];
  const float* W1    = (const float*)d_in[3];
  const float* b1    = (const float*)d_in[4];
  const float* W2    = (const float*)d_in[5];
  const float* b2    = (const float*)d_in[6];
  const float* W3    = (const float*)d_in[7];
  const float* b3    = (const float*)d_in[8];
  const float* W5    = (const float*)d_in[9];
  const float* b5    = (const float*)d_in[10];
  const float* wi    = (const float*)d_in[11];
  const float* wh    = (const float*)d_in[12];
  const float* bi    = (const float*)d_in[13];
  const float* bh    = (const float*)d_in[14];
  const float* w_end = (const float*)d_in[15];
  const float* b_end = (const float*)d_in[16];
  const int*   capp  = (const int*)d_in[17];

  float* out = (float*)d_out;
  float* x0g = (float*)d_ws;
  float* x1g = x0g + (size_t)NN*HD;

  lastgcn_kernel<<<dim3(1), dim3(NTHR), 0, stream>>>(
      feat, src, dst, W1, b1, W2, b2, W3, b3, W5, b5,
      wi, wh, bi, bh, w_end, b_end, capp, out, x0g, x1g);
}

// Round 4
// 386.473 us; speedup vs baseline: 1.4228x; 1.2438x over previous
//
#include <hip/hip_runtime.h>
#include <math.h>

#define NN 588
#define EE 9408
#define HD 64
#define NTHR 1024
#define NWAVE (NTHR/64)   // 16
#define NEGS 0.01f
#define THRESHV 0.999f
#define DROW NN           // dummy node index (row 588 of x buffers, zeroed)

__device__ __forceinline__ float lrelu(float v){ return v >= 0.f ? v : NEGS*v; }
__device__ __forceinline__ float sigm(float v){ return 1.f/(1.f+expf(-v)); }
__device__ __forceinline__ float rdlane(float v, int l){
  return __int_as_float(__builtin_amdgcn_readlane(__float_as_int(v), l));
}
__device__ __forceinline__ float wredsum(float v){
  v += __shfl_down(v,32); v += __shfl_down(v,16); v += __shfl_down(v,8);
  v += __shfl_down(v,4);  v += __shfl_down(v,2);  v += __shfl_down(v,1);
  return v;  // valid on lane 0
}
__device__ __forceinline__ void sink4(float4 v){
  asm volatile("" :: "v"(v.x), "v"(v.y), "v"(v.z), "v"(v.w));
}
// Warm L2: batches of 8 outstanding float4 loads per lane.
__device__ __forceinline__ void prefetch_region(const float* p0, int nfloats, int t, int T){
  const float4* p = (const float4*)p0;
  const int n = nfloats >> 2;
  for (int base = t; base < n; base += T*8) {
    float4 v[8];
    #pragma unroll
    for (int u = 0; u < 8; ++u) {
      int i = base + u*T; if (i >= n) i = n - 1;
      v[u] = p[i];
    }
    #pragma unroll
    for (int u = 0; u < 8; ++u) sink4(v[u]);
  }
}

__global__ __launch_bounds__(NTHR)
void lastgcn_kernel(const float* feat, const int* src, const int* dst,
                    const float* W1, const float* b1, const float* W2, const float* b2,
                    const float* W3, const float* b3, const float* W5, const float* b5,
                    const float* wi, const float* wh, const float* bi, const float* bh,
                    const float* w_end, const float* b_end, const int* capp,
                    float* out, float* x0g, float* x1g, int* eidxP) {
  const int tid  = threadIdx.x;
  const int lane = tid & 63;
  const int w    = tid >> 6;

  __shared__ float  W2L[64*64];     // 16 KB, [l*64+j]: lane j reads bank j%32 -> free
  __shared__ int    offL[NN];       // padded CSR start (multiple of 8)
  __shared__ int    degL[NN];       // real degree
  __shared__ int    curL[NN];
  __shared__ float  yL[NN+1];       // yL[588] = 0 (dummy)
  __shared__ float  inpL[NN];
  __shared__ float4 f4L[NN];
  __shared__ float  gxL[192], ghL[192], stateL[64];
  __shared__ int    wsumL[NWAVE];
  __shared__ float  sScal[3];       // s, fprob, counter
  __shared__ int    sStop;

  // ---- P0: zero counters; split: waves 0-3 degree count, waves 4-15 prefetch ----
  for (int t = tid; t < NN; t += NTHR) curL[t] = 0;
  if (tid == 0) yL[NN] = 0.f;
  __syncthreads();
  if (w < 4) {
    for (int e = tid; e < EE; e += 256) atomicAdd(&curL[dst[e]], 1);
  } else {
    if (w == 4) x0g[DROW*HD + lane] = 0.f;
    if (w == 5) x1g[DROW*HD + lane] = 0.f;
    const int pt = tid - 256;   // 0..767
    const int PT = 768;
    prefetch_region(wi,   192*NN, pt, PT);   // 451 KB
    prefetch_region(wh,   192*64, pt, PT);
    prefetch_region((const float*)src, EE, pt, PT);
    prefetch_region(W2,   64*64,  pt, PT);
    prefetch_region(feat, NN*4,   pt, PT);
    prefetch_region(W1,   4*64,   pt, PT);
    prefetch_region(bi,   192,    pt, PT);
    prefetch_region(bh,   192,    pt, PT);
    prefetch_region(W3,   64,     pt, PT);
    prefetch_region(W5,   64*3,   pt, PT);
    prefetch_region(w_end,64,     pt, PT);
  }
  __syncthreads();

  // ---- P1: padded exclusive prefix over degrees ----
  {
    int d = (tid < NN) ? curL[tid] : 0;
    int pc = (d + 7) & ~7;
    int inc = pc;
    for (int o = 1; o < 64; o <<= 1) { int u = __shfl_up(inc, o); if (lane >= o) inc += u; }
    if (lane == 63) wsumL[w] = inc;
    __syncthreads();
    if (w == 0) {
      int s0 = (lane < NWAVE) ? wsumL[lane] : 0;
      int is = s0;
      for (int o = 1; o < NWAVE; o <<= 1) { int u = __shfl_up(is, o); if (lane >= o) is += u; }
      if (lane < NWAVE) wsumL[lane] = is - s0;
    }
    __syncthreads();
    if (tid < NN) {
      int ex = wsumL[w] + inc - pc;
      offL[tid] = ex; curL[tid] = ex; degL[tid] = d;
    }
    __syncthreads();
  }

  // ---- P2: scatter src by dst into padded eidxP; fill tails with DROW; W2->LDS ----
  for (int e = tid; e < EE; e += NTHR) {
    int p = atomicAdd(&curL[dst[e]], 1);
    eidxP[p] = src[e];
  }
  for (int i = tid; i < 64*64; i += NTHR) W2L[i] = W2[i];
  __syncthreads();
  if (tid < NN) {
    int d = degL[tid], e0 = offL[tid], pc = (d + 7) & ~7;
    for (int k = d; k < pc; ++k) eidxP[e0 + k] = DROW;
  }
  __syncthreads();

  // ---- P3: conv1: feature sums, x0 = lrelu(agg@W1+b1), y0 = x0@W3 ----
  if (tid < NN) {
    int d = degL[tid], e0 = offL[tid];
    float fx=0.f, fy=0.f, fz=0.f, fw=0.f;
    for (int k = 0; k < d; k += 8) {
      int ids[8];
      *(int4*)(ids)   = *(const int4*)(eidxP + e0 + k);
      *(int4*)(ids+4) = *(const int4*)(eidxP + e0 + k + 4);
      float4 tv[8];
      #pragma unroll
      for (int u = 0; u < 8; ++u) {
        int kk = k + u;
        tv[u] = (kk < d) ? *(const float4*)(feat + ids[u]*4) : make_float4(0,0,0,0);
      }
      #pragma unroll
      for (int u = 0; u < 8; ++u) { fx += tv[u].x; fy += tv[u].y; fz += tv[u].z; fw += tv[u].w; }
    }
    f4L[tid] = make_float4(fx, fy, fz, fw);
  }
  __syncthreads();
  const float W3r = W3[lane];
  for (int n = w; n < NN; n += NWAVE) {
    float4 f = f4L[n];
    float v = b1[lane] + f.x*W1[lane] + f.y*W1[64+lane] + f.z*W1[128+lane] + f.w*W1[192+lane];
    v = lrelu(v);
    x0g[n*HD + lane] = v;
    float yv = wredsum(v * W3r);
    if (lane == 0) yL[n] = yv;
  }
  __syncthreads();

  const float b3v = b3[0];

  // ---- gx phase (macro-ish lambda): inp from yL via padded CSR, then wi matvec ----
  auto gx_phase = [&](const float* gh_or_null) {
    if (tid < NN) {
      int e0 = offL[tid], pc = (degL[tid] + 7) & ~7;
      float a = 0.f;
      for (int k = 0; k < pc; k += 8) {
        int4 i0 = *(const int4*)(eidxP + e0 + k);
        int4 i1 = *(const int4*)(eidxP + e0 + k + 4);
        a += yL[i0.x] + yL[i0.y] + yL[i0.z] + yL[i0.w];
        a += yL[i1.x] + yL[i1.y] + yL[i1.z] + yL[i1.w];
      }
      inpL[tid] = lrelu(a + b3v);
    }
    __syncthreads();
    for (int rr = 0; rr < 192/NWAVE; ++rr) {       // 12 rows per wave
      int r = w*(192/NWAVE) + rr;
      const float* row = wi + r*NN;
      float p = 0.f;
      #pragma unroll
      for (int k = 0; k < 10; ++k) {
        int c = lane + k*64;
        if (c < NN) p += row[c]*inpL[c];
      }
      p = wredsum(p);
      if (lane == 0) gxL[r] = p + bi[r];
    }
    __syncthreads();
    (void)gh_or_null;
  };

  gx_phase(nullptr);
  // ---- GRU init (h0 = 0), fprob0/s0, then gh = bh + wh@state ----
  if (w == 0) {
    int j = lane;
    float r  = sigm(gxL[j]      + bh[j]);
    float z  = sigm(gxL[64+j]   + bh[64+j]);
    float n2 = tanhf(gxL[128+j] + r*bh[128+j]);
    float st = (1.f - z)*n2;
    stateL[j] = st;
    float t2 = wredsum(st * w_end[j]);
    if (j == 0) {
      float pr = sigm(t2 + b_end[0]);
      sScal[0] = pr; sScal[1] = pr; sScal[2] = 0.f;
      sStop = (pr >= THRESHV) ? 1 : 0;
    }
  }
  __syncthreads();
  for (int rr = 0; rr < 192/NWAVE; ++rr) {
    int r = w*(192/NWAVE) + rr;
    float p = wredsum(wh[r*64 + lane] * stateL[lane]);
    if (lane == 0) ghL[r] = p + bh[r];
  }
  __syncthreads();

  // ---- main loop ----
  const int cap = capp[0];
  float* xc = x0g;
  float* xn = x1g;
  const float b2r = b2[lane];
  for (int it = 0; it < cap; ++it) {
    if (sStop) break;   // uniform

    // conv2: node pairs per wave; gather 16 rows outstanding; LDS-W2 matmul shared
    for (int n0 = w; n0 < NN; n0 += 2*NWAVE) {
      int n1 = n0 + NWAVE;
      bool has1 = (n1 < NN);
      int e0a = offL[n0], pca = (degL[n0] + 7) & ~7;
      int e0b = has1 ? offL[n1] : 0;
      int pcb = has1 ? ((degL[n1] + 7) & ~7) : 0;
      float accA = 0.f, accB = 0.f;
      int pcm = pca > pcb ? pca : pcb;
      for (int k = 0; k < pcm; k += 8) {
        float ta[8], tb[8];
        if (k < pca) {
          int ia[8];
          *(int4*)(ia)   = *(const int4*)(eidxP + e0a + k);
          *(int4*)(ia+4) = *(const int4*)(eidxP + e0a + k + 4);
          #pragma unroll
          for (int u = 0; u < 8; ++u) ta[u] = xc[ia[u]*HD + lane];
        } else {
          #pragma unroll
          for (int u = 0; u < 8; ++u) ta[u] = 0.f;
        }
        if (k < pcb) {
          int ib[8];
          *(int4*)(ib)   = *(const int4*)(eidxP + e0b + k);
          *(int4*)(ib+4) = *(const int4*)(eidxP + e0b + k + 4);
          #pragma unroll
          for (int u = 0; u < 8; ++u) tb[u] = xc[ib[u]*HD + lane];
        } else {
          #pragma unroll
          for (int u = 0; u < 8; ++u) tb[u] = 0.f;
        }
        #pragma unroll
        for (int u = 0; u < 8; ++u) { accA += ta[u]; accB += tb[u]; }
      }
      // matmul: out[j] = sum_l agg[l] * W2[l][j]; W2 row from LDS shared by pair
      float a0=0.f,a1=0.f,a2=0.f,a3=0.f;
      float c0=0.f,c1=0.f,c2=0.f,c3=0.f;
      #pragma unroll
      for (int l = 0; l < 64; l += 4) {
        float w0 = W2L[(l+0)*64 + lane];
        float w1v = W2L[(l+1)*64 + lane];
        float w2v = W2L[(l+2)*64 + lane];
        float w3v = W2L[(l+3)*64 + lane];
        a0 = fmaf(rdlane(accA,l+0), w0,  a0);  c0 = fmaf(rdlane(accB,l+0), w0,  c0);
        a1 = fmaf(rdlane(accA,l+1), w1v, a1);  c1 = fmaf(rdlane(accB,l+1), w1v, c1);
        a2 = fmaf(rdlane(accA,l+2), w2v, a2);  c2 = fmaf(rdlane(accB,l+2), w2v, c2);
        a3 = fmaf(rdlane(accA,l+3), w3v, a3);  c3 = fmaf(rdlane(accB,l+3), w3v, c3);
      }
      {
        float vA = lrelu(b2r + (a0+a1)+(a2+a3));
        xn[n0*HD + lane] = vA;
        float yv = wredsum(vA * W3r);
        if (lane == 0) yL[n0] = yv;
      }
      if (has1) {
        float vB = lrelu(b2r + (c0+c1)+(c2+c3));
        xn[n1*HD + lane] = vB;
        float yv = wredsum(vB * W3r);
        if (lane == 0) yL[n1] = yv;
      }
    }
    __syncthreads();

    gx_phase(nullptr);

    if (w == 0) {
      int j = lane;
      float r  = sigm(gxL[j]      + ghL[j]);
      float z  = sigm(gxL[64+j]   + ghL[64+j]);
      float n2 = tanhf(gxL[128+j] + r*ghL[128+j]);
      float st = (1.f - z)*n2 + z*stateL[j];   // frozen state
      float t2 = wredsum(st * w_end[j]);
      if (j == 0) {
        float pr = sigm(t2 + b_end[0]);
        float s = sScal[0] + pr;
        sScal[0] = s; sScal[1] = pr; sScal[2] += 1.f;
        sStop = (s >= THRESHV) ? 1 : 0;
      }
    }
    __syncthreads();

    float* tmp = xc; xc = xn; xn = tmp;
  }

  // ---- final conv: out = segsum(x_last) @ W5 + b5 ----
  for (int n = w; n < NN; n += NWAVE) {
    int e0 = offL[n], pc = (degL[n] + 7) & ~7;
    float acc = 0.f;
    for (int k = 0; k < pc; k += 8) {
      int ia[8];
      *(int4*)(ia)   = *(const int4*)(eidxP + e0 + k);
      *(int4*)(ia+4) = *(const int4*)(eidxP + e0 + k + 4);
      float t[8];
      #pragma unroll
      for (int u = 0; u < 8; ++u) t[u] = xc[ia[u]*HD + lane];
      #pragma unroll
      for (int u = 0; u < 8; ++u) acc += t[u];
    }
    float p0 = wredsum(acc * W5[lane*3 + 0]);
    float p1 = wredsum(acc * W5[lane*3 + 1]);
    float p2 = wredsum(acc * W5[lane*3 + 2]);
    if (lane == 0) {
      out[n*3 + 0] = p0 + b5[0];
      out[n*3 + 1] = p1 + b5[1];
      out[n*3 + 2] = p2 + b5[2];
    }
  }
  if (tid == 0) {
    out[NN*3]     = sScal[2];  // counter (as float)
    out[NN*3 + 1] = sScal[1];  // fprob
  }
}

extern "C" void kernel_launch(void* const* d_in, const int* in_sizes, int n_in,
                              void* d_out, int out_size, void* d_ws, size_t ws_size,
                              hipStream_t stream) {
  const float* feat  = (const float*)d_in[0];
  const int*   src   = (const int*)d_in[1];
  const int*   dst   = (const int*)d_in[2];
  const float* W1    = (const float*)d_in[3];
  const float* b1    = (const float*)d_in[4];
  const float* W2    = (const float*)d_in[5];
  const float* b2    = (const float*)d_in[6];
  const float* W3    = (const float*)d_in[7];
  const float* b3    = (const float*)d_in[8];
  const float* W5    = (const float*)d_in[9];
  const float* b5    = (const float*)d_in[10];
  const float* wi    = (const float*)d_in[11];
  const float* wh    = (const float*)d_in[12];
  const float* bi    = (const float*)d_in[13];
  const float* bh    = (const float*)d_in[14];
  const float* w_end = (const float*)d_in[15];
  const float* b_end = (const float*)d_in[16];
  const int*   capp  = (const int*)d_in[17];

  float* out = (float*)d_out;
  float* x0g = (float*)d_ws;                       // (NN+1)*64 floats
  float* x1g = x0g + (size_t)(NN+1)*HD;            // (NN+1)*64 floats
  int*   eidxP = (int*)(x1g + (size_t)(NN+1)*HD);  // padded CSR, <= EE + 8*NN ints

  lastgcn_kernel<<<dim3(1), dim3(NTHR), 0, stream>>>(
      feat, src, dst, W1, b1, W2, b2, W3, b3, W5, b5,
      wi, wh, bi, bh, w_end, b_end, capp, out, x0g, x1g, eidxP);
}

// Round 6
// 186.162 us; speedup vs baseline: 2.9538x; 2.0760x over previous
//
#include <hip/hip_runtime.h>
#include <math.h>

#define NN 588
#define EE 9408
#define HD 64
#define NBLK 16
#define NTHR 512
#define NWAVE (NTHR/64)   // 8
#define GXROWS (192/NBLK) // 12
#define NEGS 0.01f
#define THRESHV 0.999f
#define MAGIC 0x51CAFE17u
#define DROW NN

struct Ctrl { unsigned ready, cnt, gen, decided; unsigned pad[12]; };

__device__ __forceinline__ float lrelu(float v){ return v >= 0.f ? v : NEGS*v; }
__device__ __forceinline__ float sigm(float v){ return 1.f/(1.f+expf(-v)); }
__device__ __forceinline__ float rdlane(float v, int l){
  return __int_as_float(__builtin_amdgcn_readlane(__float_as_int(v), l));
}
__device__ __forceinline__ float wredsum(float v){
  v += __shfl_down(v,32); v += __shfl_down(v,16); v += __shfl_down(v,8);
  v += __shfl_down(v,4);  v += __shfl_down(v,2);  v += __shfl_down(v,1);
  return v;  // valid on lane 0
}

// Grid barrier: monotonic generation, relaxed spin, one threadfence each side.
__device__ __forceinline__ void gbar(Ctrl* c, unsigned& mygen) {
  __syncthreads();
  ++mygen;                      // every thread tracks the generation
  if (threadIdx.x == 0) {
    __threadfence();
    unsigned a = __hip_atomic_fetch_add(&c->cnt, 1u, __ATOMIC_ACQ_REL, __HIP_MEMORY_SCOPE_AGENT);
    if (a == (unsigned)(NBLK-1)) {
      __hip_atomic_store(&c->cnt, 0u, __ATOMIC_RELAXED, __HIP_MEMORY_SCOPE_AGENT);
      __hip_atomic_store(&c->gen, mygen, __ATOMIC_RELEASE, __HIP_MEMORY_SCOPE_AGENT);
    } else {
      long bail = 0;
      while ((int)(__hip_atomic_load(&c->gen, __ATOMIC_RELAXED, __HIP_MEMORY_SCOPE_AGENT) - mygen) < 0) {
        if (++bail > (1L<<24)) break;
      }
    }
    __threadfence();
  }
  __syncthreads();
}

__global__ __launch_bounds__(NTHR)
void lastgcn_kernel(const float* feat, const int* src, const int* dst,
                    const float* W1, const float* b1, const float* W2, const float* b2,
                    const float* W3, const float* b3, const float* W5, const float* b5,
                    const float* wi, const float* wh, const float* bi, const float* bh,
                    const float* w_end, const float* b_end, const int* capp,
                    float* out, Ctrl* ctrl, float* x0g, float* x1g,
                    float* ypub, float* inppub, float* gxpub) {
  const int tid  = threadIdx.x;
  const int lane = tid & 63;
  const int w    = tid >> 6;
  const int bid  = blockIdx.x;
  const int nbeg = (NN*bid)/NBLK;
  const int nend = (NN*(bid+1))/NBLK;
  const int cnt  = nend - nbeg;          // <= 37
  const int r0   = bid*GXROWS;

  __shared__ float  W2L[64*64];          // 16 KB
  __shared__ float  wiL[GXROWS*NN];      // 28 KB: my 12 wi rows
  __shared__ int    eidxL[2048];         // padded in-edge lists of my nodes
  __shared__ int    offL[40], curL[40], degL[40];
  __shared__ float  inpF[NN];
  __shared__ float  yF[NN+1];
  __shared__ float4 f4L[40];
  __shared__ float  stateL[64], ghL[192];
  __shared__ float  sScal[3];            // s, fprob, counter (block 0)
  __shared__ unsigned sBro;
  unsigned mygen = 0;

  // ---- init gate: block 0 zeroes control + dummy rows, releases others ----
  if (bid == 0) {
    if (tid < HD) { x0g[DROW*HD + tid] = 0.f; x1g[DROW*HD + tid] = 0.f; }
    if (tid == 0) {
      ypub[NN] = 0.f;
      __hip_atomic_store(&ctrl->cnt, 0u, __ATOMIC_RELAXED, __HIP_MEMORY_SCOPE_AGENT);
      __hip_atomic_store(&ctrl->gen, 0u, __ATOMIC_RELAXED, __HIP_MEMORY_SCOPE_AGENT);
      __hip_atomic_store(&ctrl->decided, 0u, __ATOMIC_RELAXED, __HIP_MEMORY_SCOPE_AGENT);
      __threadfence();
      __hip_atomic_store(&ctrl->ready, MAGIC, __ATOMIC_RELEASE, __HIP_MEMORY_SCOPE_AGENT);
    }
  } else if (tid == 0) {
    long bail = 0;
    while (__hip_atomic_load(&ctrl->ready, __ATOMIC_RELAXED, __HIP_MEMORY_SCOPE_AGENT) != MAGIC)
      if (++bail > (1L<<24)) break;
    __threadfence();
  }
  __syncthreads();

  // ---- stage W2 + my wi rows into LDS (float4) ----
  {
    const float4* s2 = (const float4*)W2; float4* d2 = (float4*)W2L;
    for (int i = tid; i < 1024; i += NTHR) d2[i] = s2[i];
    const float4* sw = (const float4*)(wi + r0*NN); float4* dw = (float4*)wiL;
    for (int i = tid; i < GXROWS*NN/4; i += NTHR) dw[i] = sw[i];
  }
  // ---- partition CSR build (LDS-local) ----
  for (int i = tid; i < cnt; i += NTHR) degL[i] = 0;
  __syncthreads();
  for (int e = tid; e < EE; e += NTHR) {
    int d = dst[e];
    if (d >= nbeg && d < nend) atomicAdd(&degL[d-nbeg], 1);
  }
  __syncthreads();
  if (w == 0) {
    int d  = (lane < cnt) ? degL[lane] : 0;
    int pc = (d + 7) & ~7;
    int inc = pc;
    for (int o = 1; o < 64; o <<= 1) { int u = __shfl_up(inc, o); if (lane >= o) inc += u; }
    if (lane < cnt) { offL[lane] = inc - pc; curL[lane] = inc - pc; }
  }
  __syncthreads();
  for (int e = tid; e < EE; e += NTHR) {
    int d = dst[e];
    if (d >= nbeg && d < nend) {
      int p = atomicAdd(&curL[d-nbeg], 1);
      eidxL[p] = src[e];
    }
  }
  __syncthreads();
  if (tid < cnt) {
    int d = degL[tid], o = offL[tid], pc = (d + 7) & ~7;
    for (int k = d; k < pc; ++k) eidxL[o+k] = DROW;
  }
  __syncthreads();

  // ---- conv1 on my partition: agg feat, x0 = lrelu(agg@W1+b1), y0 = x0@W3 ----
  if (tid < cnt) {
    int d = degL[tid], o = offL[tid];
    float fx=0.f, fy=0.f, fz=0.f, fw2=0.f;
    for (int k = 0; k < d; k += 8) {
      int ids[8];
      *(int4*)(ids)   = *(const int4*)(eidxL + o + k);
      *(int4*)(ids+4) = *(const int4*)(eidxL + o + k + 4);
      float4 tv[8];
      #pragma unroll
      for (int u = 0; u < 8; ++u) {
        int kk = k + u;
        tv[u] = (kk < d) ? *(const float4*)(feat + ids[u]*4) : make_float4(0,0,0,0);
      }
      #pragma unroll
      for (int u = 0; u < 8; ++u) { fx += tv[u].x; fy += tv[u].y; fz += tv[u].z; fw2 += tv[u].w; }
    }
    f4L[tid] = make_float4(fx, fy, fz, fw2);
  }
  __syncthreads();
  const float W3r = W3[lane];
  for (int i = w; i < cnt; i += NWAVE) {
    int n = nbeg + i; float4 f = f4L[i];
    float v = b1[lane] + f.x*W1[lane] + f.y*W1[64+lane] + f.z*W1[128+lane] + f.w*W1[192+lane];
    v = lrelu(v);
    x0g[n*HD + lane] = v;
    float yv = wredsum(v * W3r);
    if (lane == 0) ypub[n] = yv;
  }
  gbar(ctrl, mygen);                     // B1: x0 + y0 visible

  const float b3v = b3[0];

  // inp (my nodes) -> publish -> barrier -> gx (my 12 rows) -> publish -> barrier
  auto inp_gx = [&]() {
    for (int i = tid; i <= NN; i += NTHR) yF[i] = ypub[i];
    __syncthreads();
    if (tid < cnt) {
      int dd = degL[tid], o = offL[tid], pc = (dd + 7) & ~7;
      float a = 0.f;
      for (int k = 0; k < pc; k += 8) {
        int4 i0 = *(const int4*)(eidxL + o + k);
        int4 i1 = *(const int4*)(eidxL + o + k + 4);
        a += yF[i0.x] + yF[i0.y] + yF[i0.z] + yF[i0.w];
        a += yF[i1.x] + yF[i1.y] + yF[i1.z] + yF[i1.w];
      }
      inppub[nbeg + tid] = lrelu(a + b3v);
    }
    gbar(ctrl, mygen);                   // B_inp
    for (int i = tid; i < NN; i += NTHR) inpF[i] = inppub[i];
    __syncthreads();
    for (int rr = w; rr < GXROWS; rr += NWAVE) {
      const float* row = wiL + rr*NN;
      float p = 0.f;
      #pragma unroll
      for (int k = 0; k < 10; ++k) {
        int c = lane + (k << 6);
        if (c < NN) p += row[c]*inpF[c];
      }
      p = wredsum(p);
      if (lane == 0) gxpub[r0 + rr] = p + bi[r0 + rr];
    }
    gbar(ctrl, mygen);                   // B_gx
  };

  inp_gx();

  // ---- GRU init (block 0): state, s0/fprob0, gh, decided word ----
  if (bid == 0) {
    if (w == 0) {
      int j = lane;
      float r  = sigm(gxpub[j]      + bh[j]);
      float z  = sigm(gxpub[64+j]   + bh[64+j]);
      float n2 = tanhf(gxpub[128+j] + r*bh[128+j]);
      float st = (1.f - z)*n2;           // h0 = 0
      stateL[j] = st;
      float t2 = wredsum(st * w_end[j]);
      if (j == 0) { float pr = sigm(t2 + b_end[0]); sScal[0] = pr; sScal[1] = pr; sScal[2] = 0.f; }
    }
    __syncthreads();
    for (int r = w; r < 192; r += NWAVE) {
      float p = wredsum(wh[r*64 + lane] * stateL[lane]);
      if (lane == 0) ghL[r] = p + bh[r];
    }
    __syncthreads();
    if (tid == 0) {
      unsigned stop = (sScal[0] >= THRESHV) ? 1u : 0u;
      __hip_atomic_store(&ctrl->decided, 1u | (stop << 31), __ATOMIC_RELEASE, __HIP_MEMORY_SCOPE_AGENT);
    }
  }

  // ---- main loop ----
  const int cap = capp[0];
  float* xc = x0g;
  float* xn = x1g;
  const float b2r = b2[lane];
  for (int it = 0; it < cap; ++it) {
    if (tid == 0) {
      unsigned d; long bail = 0;
      do {
        d = __hip_atomic_load(&ctrl->decided, __ATOMIC_RELAXED, __HIP_MEMORY_SCOPE_AGENT);
        if (++bail > (1L<<24)) break;
      } while ((d & 0x7fffffffu) < (unsigned)(it + 1));
      sBro = d;
    }
    __syncthreads();
    if (sBro >> 31) break;               // uniform stop

    // conv2 on my partition: node pairs per wave, W2L matmul
    for (int i = w; i < cnt; i += 2*NWAVE) {
      int i2 = i + NWAVE;
      bool has2 = (i2 < cnt);
      int oA = offL[i],  pcA = (degL[i] + 7) & ~7;
      int oB = has2 ? offL[i2] : 0;
      int pcB = has2 ? ((degL[i2] + 7) & ~7) : 0;
      float accA = 0.f, accB = 0.f;
      int pcm = pcA > pcB ? pcA : pcB;
      for (int k = 0; k < pcm; k += 8) {
        float ta[8], tb[8];
        if (k < pcA) {
          int ia[8];
          *(int4*)(ia)   = *(const int4*)(eidxL + oA + k);
          *(int4*)(ia+4) = *(const int4*)(eidxL + oA + k + 4);
          #pragma unroll
          for (int u = 0; u < 8; ++u) ta[u] = xc[ia[u]*HD + lane];
        } else {
          for (int u = 0; u < 8; ++u) ta[u] = 0.f;
        }
        if (k < pcB) {
          int ib[8];
          *(int4*)(ib)   = *(const int4*)(eidxL + oB + k);
          *(int4*)(ib+4) = *(const int4*)(eidxL + oB + k + 4);
          #pragma unroll
          for (int u = 0; u < 8; ++u) tb[u] = xc[ib[u]*HD + lane];
        } else {
          for (int u = 0; u < 8; ++u) tb[u] = 0.f;
        }
        #pragma unroll
        for (int u = 0; u < 8; ++u) { accA += ta[u]; accB += tb[u]; }
      }
      float a0=0.f,a1=0.f,a2=0.f,a3=0.f, c0=0.f,c1=0.f,c2=0.f,c3=0.f;
      #pragma unroll
      for (int l = 0; l < 64; l += 4) {
        float w0 = W2L[(l+0)*64 + lane];
        float w1v = W2L[(l+1)*64 + lane];
        float w2v = W2L[(l+2)*64 + lane];
        float w3v = W2L[(l+3)*64 + lane];
        a0 = fmaf(rdlane(accA,l+0), w0,  a0);  c0 = fmaf(rdlane(accB,l+0), w0,  c0);
        a1 = fmaf(rdlane(accA,l+1), w1v, a1);  c1 = fmaf(rdlane(accB,l+1), w1v, c1);
        a2 = fmaf(rdlane(accA,l+2), w2v, a2);  c2 = fmaf(rdlane(accB,l+2), w2v, c2);
        a3 = fmaf(rdlane(accA,l+3), w3v, a3);  c3 = fmaf(rdlane(accB,l+3), w3v, c3);
      }
      {
        int n = nbeg + i;
        float vA = lrelu(b2r + (a0+a1)+(a2+a3));
        xn[n*HD + lane] = vA;
        float yv = wredsum(vA * W3r);
        if (lane == 0) ypub[n] = yv;
      }
      if (has2) {
        int n = nbeg + i2;
        float vB = lrelu(b2r + (c0+c1)+(c2+c3));
        xn[n*HD + lane] = vB;
        float yv = wredsum(vB * W3r);
        if (lane == 0) ypub[n] = yv;
      }
    }
    gbar(ctrl, mygen);                   // B_a: xn + y visible

    inp_gx();                            // B_inp + B_gx

    if (bid == 0 && w == 0) {
      int j = lane;
      float r  = sigm(gxpub[j]      + ghL[j]);
      float z  = sigm(gxpub[64+j]   + ghL[64+j]);
      float n2 = tanhf(gxpub[128+j] + r*ghL[128+j]);
      float st = (1.f - z)*n2 + z*stateL[j];   // frozen state
      float t2 = wredsum(st * w_end[j]);
      if (j == 0) {
        float pr = sigm(t2 + b_end[0]);
        float s = sScal[0] + pr;
        sScal[0] = s; sScal[1] = pr; sScal[2] += 1.f;
        unsigned stop = (s >= THRESHV) ? 1u : 0u;
        __hip_atomic_store(&ctrl->decided, (unsigned)(it+2) | (stop << 31),
                           __ATOMIC_RELEASE, __HIP_MEMORY_SCOPE_AGENT);
      }
    }
    { float* t = xc; xc = xn; xn = t; }
  }

  // ---- final conv on my partition: out = segsum(x_last) @ W5 + b5 ----
  for (int i = w; i < cnt; i += NWAVE) {
    int n = nbeg + i;
    int dd = degL[i], o = offL[i], pc = (dd + 7) & ~7;
    float acc = 0.f;
    for (int k = 0; k < pc; k += 8) {
      int ia[8];
      *(int4*)(ia)   = *(const int4*)(eidxL + o + k);
      *(int4*)(ia+4) = *(const int4*)(eidxL + o + k + 4);
      float t[8];
      #pragma unroll
      for (int u = 0; u < 8; ++u) t[u] = xc[ia[u]*HD + lane];
      #pragma unroll
      for (int u = 0; u < 8; ++u) acc += t[u];
    }
    float p0 = wredsum(acc * W5[lane*3 + 0]);
    float p1 = wredsum(acc * W5[lane*3 + 1]);
    float p2 = wredsum(acc * W5[lane*3 + 2]);
    if (lane == 0) {
      out[n*3 + 0] = p0 + b5[0];
      out[n*3 + 1] = p1 + b5[1];
      out[n*3 + 2] = p2 + b5[2];
    }
  }
  if (bid == 0 && tid == 0) {
    out[NN*3]     = sScal[2];  // counter (as float)
    out[NN*3 + 1] = sScal[1];  // fprob
  }
}

extern "C" void kernel_launch(void* const* d_in, const int* in_sizes, int n_in,
                              void* d_out, int out_size, void* d_ws, size_t ws_size,
                              hipStream_t stream) {
  const float* feat  = (const float*)d_in[0];
  const int*   src   = (const int*)d_in[1];
  const int*   dst   = (const int*)d_in[2];
  const float* W1    = (const float*)d_in[3];
  const float* b1    = (const float*)d_in[4];
  const float* W2    = (const float*)d_in[5];
  const float* b2    = (const float*)d_in[6];
  const float* W3    = (const float*)d_in[7];
  const float* b3    = (const float*)d_in[8];
  const float* W5    = (const float*)d_in[9];
  const float* b5    = (const float*)d_in[10];
  const float* wi    = (const float*)d_in[11];
  const float* wh    = (const float*)d_in[12];
  const float* bi    = (const float*)d_in[13];
  const float* bh    = (const float*)d_in[14];
  const float* w_end = (const float*)d_in[15];
  const float* b_end = (const float*)d_in[16];
  const int*   capp  = (const int*)d_in[17];

  float* out = (float*)d_out;
  char* wsb = (char*)d_ws;
  Ctrl*  ctrl   = (Ctrl*)wsb;
  float* x0g    = (float*)(wsb + 64);
  float* x1g    = x0g + (size_t)(NN+1)*HD;
  float* ypub   = x1g + (size_t)(NN+1)*HD;
  float* inppub = ypub + (NN+1);
  float* gxpub  = inppub + NN;

  lastgcn_kernel<<<dim3(NBLK), dim3(NTHR), 0, stream>>>(
      feat, src, dst, W1, b1, W2, b2, W3, b3, W5, b5,
      wi, wh, bi, bh, w_end, b_end, capp, out,
      ctrl, x0g, x1g, ypub, inppub, gxpub);
}

// Round 7
// 170.675 us; speedup vs baseline: 3.2218x; 1.0907x over previous
//
#include <hip/hip_runtime.h>
#include <math.h>

#define NN 588
#define EE 9408
#define HD 64
#define NBLK 16
#define NTHR 512
#define NWAVE (NTHR/64)   // 8
#define GXROWS (192/NBLK) // 12
#define NEGS 0.01f
#define THRESHV 0.999f
#define MAGIC 0x51CAFE17u
#define DROW NN
#define EPADCAP 13536     // >= 9408 + 588*7

struct Ctrl { unsigned ready, cnt, gen; unsigned pad[13]; };

__device__ __forceinline__ float lrelu(float v){ return v >= 0.f ? v : NEGS*v; }
__device__ __forceinline__ float sigm(float v){ return 1.f/(1.f+expf(-v)); }
__device__ __forceinline__ float rdlane(float v, int l){
  return __int_as_float(__builtin_amdgcn_readlane(__float_as_int(v), l));
}
__device__ __forceinline__ float wredsum(float v){
  v += __shfl_down(v,32); v += __shfl_down(v,16); v += __shfl_down(v,8);
  v += __shfl_down(v,4);  v += __shfl_down(v,2);  v += __shfl_down(v,1);
  return v;  // valid on lane 0
}

// Grid barrier: monotonic generation, relaxed spin + s_sleep, one fence each side.
__device__ __forceinline__ void gbar(Ctrl* c, unsigned& mygen) {
  __syncthreads();
  ++mygen;
  if (threadIdx.x == 0) {
    __threadfence();
    unsigned a = __hip_atomic_fetch_add(&c->cnt, 1u, __ATOMIC_ACQ_REL, __HIP_MEMORY_SCOPE_AGENT);
    if (a == (unsigned)(NBLK-1)) {
      __hip_atomic_store(&c->cnt, 0u, __ATOMIC_RELAXED, __HIP_MEMORY_SCOPE_AGENT);
      __hip_atomic_store(&c->gen, mygen, __ATOMIC_RELEASE, __HIP_MEMORY_SCOPE_AGENT);
    } else {
      long bail = 0;
      while ((int)(__hip_atomic_load(&c->gen, __ATOMIC_RELAXED, __HIP_MEMORY_SCOPE_AGENT) - mygen) < 0) {
        __builtin_amdgcn_s_sleep(1);
        if (++bail > (1L<<24)) break;
      }
    }
    __threadfence();
  }
  __syncthreads();
}

__global__ __launch_bounds__(NTHR)
void lastgcn_kernel(const float* __restrict__ feat, const int* __restrict__ src,
                    const int* __restrict__ dst,
                    const float* __restrict__ W1, const float* __restrict__ b1,
                    const float* __restrict__ W2, const float* __restrict__ b2,
                    const float* __restrict__ W3, const float* __restrict__ b3,
                    const float* __restrict__ W5, const float* __restrict__ b5,
                    const float* __restrict__ wi, const float* __restrict__ wh,
                    const float* __restrict__ bi, const float* __restrict__ bh,
                    const float* __restrict__ w_end, const float* __restrict__ b_end,
                    const int* __restrict__ capp,
                    float* __restrict__ out, Ctrl* ctrl,
                    float* __restrict__ x0g, float* __restrict__ x1g,
                    float* __restrict__ ypub, float* __restrict__ gxpub) {
  const int tid  = threadIdx.x;
  const int lane = tid & 63;
  const int w    = tid >> 6;
  const int bid  = blockIdx.x;
  const int nbeg = (NN*bid)/NBLK;
  const int nend = (NN*(bid+1))/NBLK;
  const int cnt  = nend - nbeg;          // 36 or 37
  const int r0   = bid*GXROWS;

  __shared__ float  W2L[64*64];          // 16384 B
  __shared__ unsigned short eidxL[EPADCAP]; // 27072 B: full padded CSR (u16)
  __shared__ int    offL[NN+1];          // 2356
  __shared__ int    curL[NN];            // 2352
  __shared__ unsigned short degU[NN];    // 1176
  __shared__ float  yF[NN+1];            // 2356
  __shared__ float  inpF[NN];            // 2352
  __shared__ float  ghL[192], stateL[64];
  __shared__ float4 f4L[40];
  __shared__ int    sScan[NTHR];         // 2048
  __shared__ float  sScal[3];            // s, fprob, counter (replicated per block)
  __shared__ int    sStop;
  unsigned mygen = 0;

  // ---- init gate ----
  if (bid == 0) {
    if (tid < HD) { x0g[DROW*HD + tid] = 0.f; x1g[DROW*HD + tid] = 0.f; }
    if (tid == 0) {
      ypub[NN] = 0.f;
      __hip_atomic_store(&ctrl->cnt, 0u, __ATOMIC_RELAXED, __HIP_MEMORY_SCOPE_AGENT);
      __hip_atomic_store(&ctrl->gen, 0u, __ATOMIC_RELAXED, __HIP_MEMORY_SCOPE_AGENT);
      __threadfence();
      __hip_atomic_store(&ctrl->ready, MAGIC, __ATOMIC_RELEASE, __HIP_MEMORY_SCOPE_AGENT);
    }
  } else if (tid == 0) {
    long bail = 0;
    while (__hip_atomic_load(&ctrl->ready, __ATOMIC_RELAXED, __HIP_MEMORY_SCOPE_AGENT) != MAGIC) {
      __builtin_amdgcn_s_sleep(1);
      if (++bail > (1L<<24)) break;
    }
    __threadfence();
  }
  __syncthreads();

  // ---- full CSR build in LDS (u16, per-node pad to x8 with DROW) ----
  for (int i = tid; i < NN; i += NTHR) curL[i] = 0;
  for (int i = tid; i < 1024; i += NTHR) ((float4*)W2L)[i] = ((const float4*)W2)[i];
  __syncthreads();
  for (int e = tid; e < EE; e += NTHR) atomicAdd(&curL[dst[e]], 1);
  __syncthreads();
  {
    const int n0 = 2*tid, n1 = 2*tid + 1;
    int d0 = (n0 < NN) ? curL[n0] : 0;
    int d1 = (n1 < NN) ? curL[n1] : 0;
    int p0 = (d0 + 7) & ~7, p1 = (d1 + 7) & ~7;
    int mysum = p0 + p1;
    sScan[tid] = mysum;
    __syncthreads();
    for (int o = 1; o < NTHR; o <<= 1) {
      int v = (tid >= o) ? sScan[tid-o] : 0;
      __syncthreads();
      sScan[tid] += v;
      __syncthreads();
    }
    int run = sScan[tid] - mysum;
    if (n0 < NN) { offL[n0] = run;      curL[n0] = run;      degU[n0] = (unsigned short)d0; }
    if (n1 < NN) { offL[n1] = run + p0; curL[n1] = run + p0; degU[n1] = (unsigned short)d1; }
    if (tid == NTHR-1) offL[NN] = sScan[NTHR-1];
  }
  __syncthreads();
  for (int e = tid; e < EE; e += NTHR) {
    int p = atomicAdd(&curL[dst[e]], 1);
    eidxL[p] = (unsigned short)src[e];
  }
  __syncthreads();
  {
    const int n0 = 2*tid, n1 = 2*tid + 1;
    if (n0 < NN) for (int k = curL[n0]; k < offL[n0+1]; ++k) eidxL[k] = (unsigned short)DROW;
    if (n1 < NN) for (int k = curL[n1]; k < offL[n1+1]; ++k) eidxL[k] = (unsigned short)DROW;
  }
  __syncthreads();

  // ---- conv1 on my partition ----
  if (tid < cnt) {
    int n = nbeg + tid;
    int d = degU[n], o = offL[n];
    float fx=0.f, fy=0.f, fz=0.f, fw2=0.f;
    for (int k = 0; k < d; k += 8) {
      float4 tv[8];
      #pragma unroll
      for (int u = 0; u < 8; ++u) {
        int kk = k + u;
        tv[u] = (kk < d) ? *(const float4*)(feat + (int)eidxL[o+kk]*4) : make_float4(0,0,0,0);
      }
      #pragma unroll
      for (int u = 0; u < 8; ++u) { fx += tv[u].x; fy += tv[u].y; fz += tv[u].z; fw2 += tv[u].w; }
    }
    f4L[tid] = make_float4(fx, fy, fz, fw2);
  }
  __syncthreads();
  const float W3r = W3[lane];
  for (int i = w; i < cnt; i += NWAVE) {
    int n = nbeg + i; float4 f = f4L[i];
    float v = b1[lane] + f.x*W1[lane] + f.y*W1[64+lane] + f.z*W1[128+lane] + f.w*W1[192+lane];
    v = lrelu(v);
    x0g[n*HD + lane] = v;
    float yv = wredsum(v * W3r);
    if (lane == 0) ypub[n] = yv;
  }
  gbar(ctrl, mygen);                     // B1: x0 + y0 visible

  const float b3v = b3[0];

  // inp (ALL nodes, LDS-local) then my 12 gx rows -> publish -> barrier
  auto inp_gx = [&]() {
    for (int i = tid; i <= NN; i += NTHR) yF[i] = ypub[i];
    __syncthreads();
    for (int n = tid; n < NN; n += NTHR) {
      int o = offL[n], o1 = offL[n+1];
      float a = 0.f;
      for (int k = o; k < o1; k += 8) {
        a += yF[eidxL[k+0]] + yF[eidxL[k+1]] + yF[eidxL[k+2]] + yF[eidxL[k+3]];
        a += yF[eidxL[k+4]] + yF[eidxL[k+5]] + yF[eidxL[k+6]] + yF[eidxL[k+7]];
      }
      inpF[n] = lrelu(a + b3v);
    }
    __syncthreads();
    for (int rr = w; rr < GXROWS; rr += NWAVE) {
      const float* row = wi + (r0 + rr)*NN;
      float p = 0.f;
      #pragma unroll
      for (int k = 0; k < 10; ++k) {
        int c = lane + (k << 6);
        if (c < NN) p += row[c]*inpF[c];
      }
      p = wredsum(p);
      if (lane == 0) gxpub[r0 + rr] = p + bi[r0 + rr];
    }
    gbar(ctrl, mygen);                   // B_gx
  };

  inp_gx();

  // ---- GRU init, REPLICATED in every block (deterministic) ----
  if (w == 0) {
    int j = lane;
    float r  = sigm(gxpub[j]      + bh[j]);
    float z  = sigm(gxpub[64+j]   + bh[64+j]);
    float n2 = tanhf(gxpub[128+j] + r*bh[128+j]);
    float st = (1.f - z)*n2;             // h0 = 0
    stateL[j] = st;
    float t2 = wredsum(st * w_end[j]);
    if (j == 0) {
      float pr = sigm(t2 + b_end[0]);
      sScal[0] = pr; sScal[1] = pr; sScal[2] = 0.f;
      sStop = (pr >= THRESHV) ? 1 : 0;
    }
  }
  __syncthreads();
  for (int r = w; r < 192; r += NWAVE) {   // gh = bh + wh @ state (frozen)
    float p = wredsum(wh[r*64 + lane] * stateL[lane]);
    if (lane == 0) ghL[r] = p + bh[r];
  }
  __syncthreads();

  // ---- main loop ----
  const int cap = capp[0];
  float* xc = x0g;
  float* xn = x1g;
  const float b2r = b2[lane];
  for (int it = 0; it < cap; ++it) {
    if (sStop) break;                    // uniform across blocks (replicated GRU)

    // conv2 on my partition: node pairs per wave, W2L matmul
    for (int i = w; i < cnt; i += 2*NWAVE) {
      int i2 = i + NWAVE;
      bool has2 = (i2 < cnt);
      int nA = nbeg + i, nB = nbeg + (has2 ? i2 : i);
      int oA = offL[nA], eA = offL[nA+1];
      int oB = offL[nB], eB = offL[nB+1];
      float accA = 0.f, accB = 0.f;
      int lA = eA - oA, lB = eB - oB;
      int pcm = lA > lB ? lA : lB;
      for (int k = 0; k < pcm; k += 8) {
        float ta[8], tb[8];
        if (k < lA) {
          #pragma unroll
          for (int u = 0; u < 8; ++u) ta[u] = xc[(int)eidxL[oA+k+u]*HD + lane];
        } else {
          for (int u = 0; u < 8; ++u) ta[u] = 0.f;
        }
        if (k < lB) {
          #pragma unroll
          for (int u = 0; u < 8; ++u) tb[u] = xc[(int)eidxL[oB+k+u]*HD + lane];
        } else {
          for (int u = 0; u < 8; ++u) tb[u] = 0.f;
        }
        #pragma unroll
        for (int u = 0; u < 8; ++u) { accA += ta[u]; accB += tb[u]; }
      }
      float a0=0.f,a1=0.f,a2=0.f,a3=0.f, c0=0.f,c1=0.f,c2=0.f,c3=0.f;
      #pragma unroll
      for (int l = 0; l < 64; l += 4) {
        float w0 = W2L[(l+0)*64 + lane];
        float w1v = W2L[(l+1)*64 + lane];
        float w2v = W2L[(l+2)*64 + lane];
        float w3v = W2L[(l+3)*64 + lane];
        a0 = fmaf(rdlane(accA,l+0), w0,  a0);  c0 = fmaf(rdlane(accB,l+0), w0,  c0);
        a1 = fmaf(rdlane(accA,l+1), w1v, a1);  c1 = fmaf(rdlane(accB,l+1), w1v, c1);
        a2 = fmaf(rdlane(accA,l+2), w2v, a2);  c2 = fmaf(rdlane(accB,l+2), w2v, c2);
        a3 = fmaf(rdlane(accA,l+3), w3v, a3);  c3 = fmaf(rdlane(accB,l+3), w3v, c3);
      }
      {
        float vA = lrelu(b2r + (a0+a1)+(a2+a3));
        xn[nA*HD + lane] = vA;
        float yv = wredsum(vA * W3r);
        if (lane == 0) ypub[nA] = yv;
      }
      if (has2) {
        float vB = lrelu(b2r + (c0+c1)+(c2+c3));
        xn[nB*HD + lane] = vB;
        float yv = wredsum(vB * W3r);
        if (lane == 0) ypub[nB] = yv;
      }
    }
    gbar(ctrl, mygen);                   // B_a: xn + y visible

    inp_gx();                            // inp(LDS) + gx + B_gx

    // GRU tail, replicated
    if (w == 0) {
      int j = lane;
      float r  = sigm(gxpub[j]      + ghL[j]);
      float z  = sigm(gxpub[64+j]   + ghL[64+j]);
      float n2 = tanhf(gxpub[128+j] + r*ghL[128+j]);
      float st = (1.f - z)*n2 + z*stateL[j];   // frozen state
      float t2 = wredsum(st * w_end[j]);
      if (j == 0) {
        float pr = sigm(t2 + b_end[0]);
        float s = sScal[0] + pr;
        sScal[0] = s; sScal[1] = pr; sScal[2] += 1.f;
        sStop = (s >= THRESHV) ? 1 : 0;
      }
    }
    __syncthreads();
    { float* t = xc; xc = xn; xn = t; }
  }

  // ---- final conv on my partition ----
  for (int i = w; i < cnt; i += NWAVE) {
    int n = nbeg + i;
    int o = offL[n], o1 = offL[n+1];
    float acc = 0.f;
    for (int k = o; k < o1; k += 8) {
      float t[8];
      #pragma unroll
      for (int u = 0; u < 8; ++u) t[u] = xc[(int)eidxL[k+u]*HD + lane];
      #pragma unroll
      for (int u = 0; u < 8; ++u) acc += t[u];
    }
    float p0 = wredsum(acc * W5[lane*3 + 0]);
    float p1 = wredsum(acc * W5[lane*3 + 1]);
    float p2 = wredsum(acc * W5[lane*3 + 2]);
    if (lane == 0) {
      out[n*3 + 0] = p0 + b5[0];
      out[n*3 + 1] = p1 + b5[1];
      out[n*3 + 2] = p2 + b5[2];
    }
  }
  if (bid == 0 && tid == 0) {
    out[NN*3]     = sScal[2];  // counter (as float)
    out[NN*3 + 1] = sScal[1];  // fprob
  }
}

extern "C" void kernel_launch(void* const* d_in, const int* in_sizes, int n_in,
                              void* d_out, int out_size, void* d_ws, size_t ws_size,
                              hipStream_t stream) {
  const float* feat  = (const float*)d_in[0];
  const int*   src   = (const int*)d_in[1];
  const int*   dst   = (const int*)d_in[2];
  const float* W1    = (const float*)d_in[3];
  const float* b1    = (const float*)d_in[4];
  const float* W2    = (const float*)d_in[5];
  const float* b2    = (const float*)d_in[6];
  const float* W3    = (const float*)d_in[7];
  const float* b3    = (const float*)d_in[8];
  const float* W5    = (const float*)d_in[9];
  const float* b5    = (const float*)d_in[10];
  const float* wi    = (const float*)d_in[11];
  const float* wh    = (const float*)d_in[12];
  const float* bi    = (const float*)d_in[13];
  const float* bh    = (const float*)d_in[14];
  const float* w_end = (const float*)d_in[15];
  const float* b_end = (const float*)d_in[16];
  const int*   capp  = (const int*)d_in[17];

  float* out = (float*)d_out;
  char* wsb = (char*)d_ws;
  Ctrl*  ctrl   = (Ctrl*)wsb;
  float* x0g    = (float*)(wsb + 64);
  float* x1g    = x0g + (size_t)(NN+1)*HD;
  float* ypub   = x1g + (size_t)(NN+1)*HD;
  float* gxpub  = ypub + (NN+1);

  lastgcn_kernel<<<dim3(NBLK), dim3(NTHR), 0, stream>>>(
      feat, src, dst, W1, b1, W2, b2, W3, b3, W5, b5,
      wi, wh, bi, bh, w_end, b_end, capp, out,
      ctrl, x0g, x1g, ypub, gxpub);
}

// Round 8
// 168.335 us; speedup vs baseline: 3.2666x; 1.0139x over previous
//
#include <hip/hip_runtime.h>
#include <math.h>

#define NN 588
#define EE 9408
#define HD 64
#define NBLK 16
#define NTHR 512
#define NWAVE (NTHR/64)   // 8
#define GXROWS (192/NBLK) // 12
#define NEGS 0.01f
#define THRESHV 0.999f
#define MAGIC 0x51CAFE17u
#define DROW NN
#define EPADCAP 13536     // >= 9408 + 588*7

struct Ctrl {
  unsigned ready;  unsigned pad0[15];
  unsigned gen;    unsigned pad1[15];
  unsigned flags[NBLK*16];   // one 64B line per block
};

__device__ __forceinline__ float lrelu(float v){ return v >= 0.f ? v : NEGS*v; }
__device__ __forceinline__ float sigm(float v){ return 1.f/(1.f+expf(-v)); }
__device__ __forceinline__ float rdlane(float v, int l){
  return __int_as_float(__builtin_amdgcn_readlane(__float_as_int(v), l));
}
__device__ __forceinline__ float wredsum(float v){
  v += __shfl_down(v,32); v += __shfl_down(v,16); v += __shfl_down(v,8);
  v += __shfl_down(v,4);  v += __shfl_down(v,2);  v += __shfl_down(v,1);
  return v;  // valid on lane 0
}
__device__ __forceinline__ void sink4(float4 v){
  asm volatile("" :: "v"(v.x), "v"(v.y), "v"(v.z), "v"(v.w));
}
__device__ __forceinline__ void prefetch_region(const float* p0, int nfloats, int t, int T){
  const float4* p = (const float4*)p0;
  const int n = nfloats >> 2;
  for (int base = t; base < n; base += T*8) {
    float4 v[8];
    #pragma unroll
    for (int u = 0; u < 8; ++u) { int i = base + u*T; if (i >= n) i = n - 1; v[u] = p[i]; }
    #pragma unroll
    for (int u = 0; u < 8; ++u) sink4(v[u]);
  }
}

// Flag-tree grid barrier: parallel per-block flag stores; block 0 polls + releases.
__device__ __forceinline__ void gbar(Ctrl* c, unsigned& mygen, int bid) {
  __syncthreads();
  ++mygen;
  if (bid == 0) {
    if ((threadIdx.x >> 6) == 0) {
      int lane = threadIdx.x & 63;
      const unsigned* fp = &c->flags[(lane+1)*16];
      long bail = 0;
      for (;;) {
        int ok = (lane >= NBLK-1) ? 1 :
                 (__hip_atomic_load(fp, __ATOMIC_RELAXED, __HIP_MEMORY_SCOPE_AGENT) >= mygen);
        if (__all(ok)) break;
        __builtin_amdgcn_s_sleep(1);
        if (++bail > (1L<<22)) break;
      }
      if (lane == 0) {
        __threadfence();   // flush own writes + invalidate before release
        __hip_atomic_store(&c->gen, mygen, __ATOMIC_RELEASE, __HIP_MEMORY_SCOPE_AGENT);
      }
    }
  } else if (threadIdx.x == 0) {
    __threadfence();       // release: my data visible before flag
    __hip_atomic_store(&c->flags[bid*16], mygen, __ATOMIC_RELEASE, __HIP_MEMORY_SCOPE_AGENT);
    long bail = 0;
    while (__hip_atomic_load(&c->gen, __ATOMIC_RELAXED, __HIP_MEMORY_SCOPE_AGENT) < mygen) {
      __builtin_amdgcn_s_sleep(1);
      if (++bail > (1L<<22)) break;
    }
    __threadfence();       // acquire: invalidate so fresh data is read
  }
  __syncthreads();
}

__global__ __launch_bounds__(NTHR)
void lastgcn_kernel(const float* __restrict__ feat, const int* __restrict__ src,
                    const int* __restrict__ dst,
                    const float* __restrict__ W1, const float* __restrict__ b1,
                    const float* __restrict__ W2, const float* __restrict__ b2,
                    const float* __restrict__ W3, const float* __restrict__ b3,
                    const float* __restrict__ W5, const float* __restrict__ b5,
                    const float* __restrict__ wi, const float* __restrict__ wh,
                    const float* __restrict__ bi, const float* __restrict__ bh,
                    const float* __restrict__ w_end, const float* __restrict__ b_end,
                    const int* __restrict__ capp,
                    float* __restrict__ out, Ctrl* ctrl,
                    float* __restrict__ x0g, float* __restrict__ x1g,
                    float* __restrict__ ypub, float* __restrict__ gxpub) {
  const int tid  = threadIdx.x;
  const int lane = tid & 63;
  const int w    = tid >> 6;
  const int bid  = blockIdx.x;
  const int nbeg = (NN*bid)/NBLK;
  const int nend = (NN*(bid+1))/NBLK;
  const int cnt  = nend - nbeg;          // 36 or 37
  const int r0   = bid*GXROWS;

  __shared__ float  W2L[64*64];             // 16384 B
  __shared__ unsigned short eidxL[EPADCAP]; // 27072 B
  __shared__ int    offL[NN+1];
  __shared__ int    curL[NN];
  __shared__ unsigned short degU[NN];
  __shared__ float  yF[NN+1];
  __shared__ float  inpF[NN];
  __shared__ float  ghL[192], stateL[64];
  __shared__ float4 f4L[40];
  __shared__ int    wsumL[NWAVE];
  __shared__ float  sScal[3];
  __shared__ int    sStop;
  unsigned mygen = 0;

  // ---- init gate ----
  if (bid == 0) {
    if (tid < HD) { x0g[DROW*HD + tid] = 0.f; x1g[DROW*HD + tid] = 0.f; }
    if (tid == 64 + 0) ypub[NN] = 0.f;
    if (tid >= 128 && tid < 128 + NBLK*16 + 32) {
      // zero gen + flags region (gen at word16, flags at words 32..)
      ((unsigned*)ctrl)[tid - 128 + 16] = 0u;
    }
    __syncthreads();
    if (tid == 0) {
      __threadfence();
      __hip_atomic_store(&ctrl->ready, MAGIC, __ATOMIC_RELEASE, __HIP_MEMORY_SCOPE_AGENT);
    }
  } else if (tid == 0) {
    long bail = 0;
    while (__hip_atomic_load(&ctrl->ready, __ATOMIC_RELAXED, __HIP_MEMORY_SCOPE_AGENT) != MAGIC) {
      __builtin_amdgcn_s_sleep(1);
      if (++bail > (1L<<24)) break;
    }
    __threadfence();
  }
  __syncthreads();

  // ---- CSR build: waves 0-3 count degrees; waves 4-7 prefetch wi rows + wh ----
  for (int i = tid; i < NN; i += NTHR) curL[i] = 0;
  for (int i = tid; i < 1024; i += NTHR) ((float4*)W2L)[i] = ((const float4*)W2)[i];
  __syncthreads();
  if (w < 4) {
    for (int e = tid; e < EE; e += 256) atomicAdd(&curL[dst[e]], 1);
  } else {
    const int pt = tid - 256, PT = 256;
    prefetch_region(wi + r0*NN, GXROWS*NN, pt, PT);  // my 12 rows (28 KB)
    prefetch_region(wh, 192*64, pt, PT);             // 48 KB
    prefetch_region(w_end, 64, pt, PT);
  }
  __syncthreads();

  // ---- padded exclusive scan (wave-level, 2 stages) ----
  {
    const int n0 = 2*tid, n1 = n0 + 1;
    int d0 = (n0 < NN) ? curL[n0] : 0;
    int d1 = (n1 < NN) ? curL[n1] : 0;
    int p0 = (d0 + 7) & ~7, p1 = (d1 + 7) & ~7;
    int my = p0 + p1;
    int inc = my;
    for (int o = 1; o < 64; o <<= 1) { int u = __shfl_up(inc, o); if (lane >= o) inc += u; }
    if (lane == 63) wsumL[w] = inc;
    __syncthreads();
    if (w == 0 && lane < NWAVE) {
      int s0 = wsumL[lane];
      int is = s0;
      for (int o = 1; o < NWAVE; o <<= 1) { int u = __shfl_up(is, o); if (lane >= o) is += u; }
      wsumL[lane] = is - s0;   // exclusive
    }
    __syncthreads();
    int base = wsumL[w] + inc - my;
    if (n0 < NN) { offL[n0] = base;      curL[n0] = base;      degU[n0] = (unsigned short)d0; }
    if (n1 < NN) { offL[n1] = base + p0; curL[n1] = base + p0; degU[n1] = (unsigned short)d1; }
    if (tid == NTHR-1) offL[NN] = base + p0 + p1;
  }
  __syncthreads();
  for (int e = tid; e < EE; e += NTHR) {
    int p = atomicAdd(&curL[dst[e]], 1);
    eidxL[p] = (unsigned short)src[e];
  }
  __syncthreads();
  {
    const int n0 = 2*tid, n1 = n0 + 1;
    if (n0 < NN) for (int k = curL[n0]; k < offL[n0+1]; ++k) eidxL[k] = (unsigned short)DROW;
    if (n1 < NN) for (int k = curL[n1]; k < offL[n1+1]; ++k) eidxL[k] = (unsigned short)DROW;
  }
  __syncthreads();

  // ---- conv1 on my partition (uint4 index unpack, masked loads) ----
  if (tid < cnt) {
    int n = nbeg + tid;
    int o = offL[n], o1 = offL[n+1];
    float fx=0.f, fy=0.f, fz=0.f, fw2=0.f;
    for (int k = o; k < o1; k += 8) {
      uint4 q = *(const uint4*)(eidxL + k);
      int id[8] = { (int)(q.x & 0xFFFF), (int)(q.x >> 16), (int)(q.y & 0xFFFF), (int)(q.y >> 16),
                    (int)(q.z & 0xFFFF), (int)(q.z >> 16), (int)(q.w & 0xFFFF), (int)(q.w >> 16) };
      float4 tv[8]; float m[8];
      #pragma unroll
      for (int u = 0; u < 8; ++u) {
        int valid = id[u] < NN;
        m[u] = valid ? 1.f : 0.f;
        tv[u] = *(const float4*)(feat + (valid ? id[u] : 0)*4);
      }
      #pragma unroll
      for (int u = 0; u < 8; ++u) { fx += m[u]*tv[u].x; fy += m[u]*tv[u].y; fz += m[u]*tv[u].z; fw2 += m[u]*tv[u].w; }
    }
    f4L[tid] = make_float4(fx, fy, fz, fw2);
  }
  __syncthreads();
  const float W3r = W3[lane];
  for (int i = w; i < cnt; i += NWAVE) {
    int n = nbeg + i; float4 f = f4L[i];
    float v = b1[lane] + f.x*W1[lane] + f.y*W1[64+lane] + f.z*W1[128+lane] + f.w*W1[192+lane];
    v = lrelu(v);
    x0g[n*HD + lane] = v;
    float yv = wredsum(v * W3r);
    if (lane == 0) ypub[n] = yv;
  }
  gbar(ctrl, mygen, bid);                // B1: x0 + y0 visible

  const float b3v = b3[0];

  // inp (ALL nodes, LDS) then my 12 gx rows -> publish -> barrier
  auto inp_gx = [&]() {
    for (int i = tid; i <= NN; i += NTHR) yF[i] = ypub[i];
    __syncthreads();
    for (int n = tid; n < NN; n += NTHR) {
      int o = offL[n], o1 = offL[n+1];
      float a = 0.f;
      for (int k = o; k < o1; k += 8) {
        uint4 q = *(const uint4*)(eidxL + k);
        a += yF[q.x & 0xFFFF] + yF[q.x >> 16] + yF[q.y & 0xFFFF] + yF[q.y >> 16];
        a += yF[q.z & 0xFFFF] + yF[q.z >> 16] + yF[q.w & 0xFFFF] + yF[q.w >> 16];
      }
      inpF[n] = lrelu(a + b3v);
    }
    __syncthreads();
    const float4* inp4 = (const float4*)inpF;   // 147 float4s
    for (int rr = w; rr < GXROWS; rr += NWAVE) {
      const float4* row4 = (const float4*)(wi + (r0 + rr)*NN);
      float p = 0.f;
      #pragma unroll
      for (int k = 0; k < 3; ++k) {
        int c = lane + (k << 6);
        if (c < 147) {
          float4 a = row4[c], b = inp4[c];
          p += a.x*b.x + a.y*b.y + a.z*b.z + a.w*b.w;
        }
      }
      p = wredsum(p);
      if (lane == 0) gxpub[r0 + rr] = p + bi[r0 + rr];
    }
    gbar(ctrl, mygen, bid);              // B_gx
  };

  inp_gx();

  // ---- GRU init, replicated in every block ----
  if (w == 0) {
    int j = lane;
    float r  = sigm(gxpub[j]      + bh[j]);
    float z  = sigm(gxpub[64+j]   + bh[64+j]);
    float n2 = tanhf(gxpub[128+j] + r*bh[128+j]);
    float st = (1.f - z)*n2;             // h0 = 0
    stateL[j] = st;
    float t2 = wredsum(st * w_end[j]);
    if (j == 0) {
      float pr = sigm(t2 + b_end[0]);
      sScal[0] = pr; sScal[1] = pr; sScal[2] = 0.f;
      sStop = (pr >= THRESHV) ? 1 : 0;
    }
  }
  __syncthreads();
  for (int r = w; r < 192; r += NWAVE) {   // gh = bh + wh @ state (frozen)
    float p = wredsum(wh[r*64 + lane] * stateL[lane]);
    if (lane == 0) ghL[r] = p + bh[r];
  }
  __syncthreads();

  // ---- main loop ----
  const int cap = capp[0];
  float* xc = x0g;
  float* xn = x1g;
  const float b2r = b2[lane];
  for (int it = 0; it < cap; ++it) {
    if (sStop) break;                    // uniform (replicated GRU)

    // conv2: node pairs per wave; wave-uniform uint4 index broadcast
    for (int i = w; i < cnt; i += 2*NWAVE) {
      int i2 = i + NWAVE;
      bool has2 = (i2 < cnt);
      int nA = nbeg + i, nB = nbeg + (has2 ? i2 : i);
      int oA = offL[nA], lA = offL[nA+1] - oA;
      int oB = offL[nB], lB = offL[nB+1] - oB;
      float accA = 0.f, accB = 0.f;
      int pcm = lA > lB ? lA : lB;
      for (int k = 0; k < pcm; k += 8) {
        float ta[8], tb[8];
        if (k < lA) {
          uint4 q = *(const uint4*)(eidxL + oA + k);
          ta[0] = xc[(int)(q.x & 0xFFFF)*HD + lane]; ta[1] = xc[(int)(q.x >> 16)*HD + lane];
          ta[2] = xc[(int)(q.y & 0xFFFF)*HD + lane]; ta[3] = xc[(int)(q.y >> 16)*HD + lane];
          ta[4] = xc[(int)(q.z & 0xFFFF)*HD + lane]; ta[5] = xc[(int)(q.z >> 16)*HD + lane];
          ta[6] = xc[(int)(q.w & 0xFFFF)*HD + lane]; ta[7] = xc[(int)(q.w >> 16)*HD + lane];
        } else { for (int u = 0; u < 8; ++u) ta[u] = 0.f; }
        if (k < lB) {
          uint4 q = *(const uint4*)(eidxL + oB + k);
          tb[0] = xc[(int)(q.x & 0xFFFF)*HD + lane]; tb[1] = xc[(int)(q.x >> 16)*HD + lane];
          tb[2] = xc[(int)(q.y & 0xFFFF)*HD + lane]; tb[3] = xc[(int)(q.y >> 16)*HD + lane];
          tb[4] = xc[(int)(q.z & 0xFFFF)*HD + lane]; tb[5] = xc[(int)(q.z >> 16)*HD + lane];
          tb[6] = xc[(int)(q.w & 0xFFFF)*HD + lane]; tb[7] = xc[(int)(q.w >> 16)*HD + lane];
        } else { for (int u = 0; u < 8; ++u) tb[u] = 0.f; }
        #pragma unroll
        for (int u = 0; u < 8; ++u) { accA += ta[u]; accB += tb[u]; }
      }
      float a0=0.f,a1=0.f,a2=0.f,a3=0.f, c0=0.f,c1=0.f,c2=0.f,c3=0.f;
      #pragma unroll
      for (int l = 0; l < 64; l += 4) {
        float w0 = W2L[(l+0)*64 + lane];
        float w1v = W2L[(l+1)*64 + lane];
        float w2v = W2L[(l+2)*64 + lane];
        float w3v = W2L[(l+3)*64 + lane];
        a0 = fmaf(rdlane(accA,l+0), w0,  a0);  c0 = fmaf(rdlane(accB,l+0), w0,  c0);
        a1 = fmaf(rdlane(accA,l+1), w1v, a1);  c1 = fmaf(rdlane(accB,l+1), w1v, c1);
        a2 = fmaf(rdlane(accA,l+2), w2v, a2);  c2 = fmaf(rdlane(accB,l+2), w2v, c2);
        a3 = fmaf(rdlane(accA,l+3), w3v, a3);  c3 = fmaf(rdlane(accB,l+3), w3v, c3);
      }
      {
        float vA = lrelu(b2r + (a0+a1)+(a2+a3));
        xn[nA*HD + lane] = vA;
        float yv = wredsum(vA * W3r);
        if (lane == 0) ypub[nA] = yv;
      }
      if (has2) {
        float vB = lrelu(b2r + (c0+c1)+(c2+c3));
        xn[nB*HD + lane] = vB;
        float yv = wredsum(vB * W3r);
        if (lane == 0) ypub[nB] = yv;
      }
    }
    gbar(ctrl, mygen, bid);              // B_a: xn + y visible

    inp_gx();                            // inp + gx + B_gx

    if (w == 0) {                        // GRU tail, replicated
      int j = lane;
      float r  = sigm(gxpub[j]      + ghL[j]);
      float z  = sigm(gxpub[64+j]   + ghL[64+j]);
      float n2 = tanhf(gxpub[128+j] + r*ghL[128+j]);
      float st = (1.f - z)*n2 + z*stateL[j];   // frozen state
      float t2 = wredsum(st * w_end[j]);
      if (j == 0) {
        float pr = sigm(t2 + b_end[0]);
        float s = sScal[0] + pr;
        sScal[0] = s; sScal[1] = pr; sScal[2] += 1.f;
        sStop = (s >= THRESHV) ? 1 : 0;
      }
    }
    __syncthreads();
    { float* t = xc; xc = xn; xn = t; }
  }

  // ---- final conv on my partition ----
  for (int i = w; i < cnt; i += NWAVE) {
    int n = nbeg + i;
    int o = offL[n], o1 = offL[n+1];
    float acc = 0.f;
    for (int k = o; k < o1; k += 8) {
      uint4 q = *(const uint4*)(eidxL + k);
      float t[8];
      t[0] = xc[(int)(q.x & 0xFFFF)*HD + lane]; t[1] = xc[(int)(q.x >> 16)*HD + lane];
      t[2] = xc[(int)(q.y & 0xFFFF)*HD + lane]; t[3] = xc[(int)(q.y >> 16)*HD + lane];
      t[4] = xc[(int)(q.z & 0xFFFF)*HD + lane]; t[5] = xc[(int)(q.z >> 16)*HD + lane];
      t[6] = xc[(int)(q.w & 0xFFFF)*HD + lane]; t[7] = xc[(int)(q.w >> 16)*HD + lane];
      #pragma unroll
      for (int u = 0; u < 8; ++u) acc += t[u];
    }
    float p0 = wredsum(acc * W5[lane*3 + 0]);
    float p1 = wredsum(acc * W5[lane*3 + 1]);
    float p2 = wredsum(acc * W5[lane*3 + 2]);
    if (lane == 0) {
      out[n*3 + 0] = p0 + b5[0];
      out[n*3 + 1] = p1 + b5[1];
      out[n*3 + 2] = p2 + b5[2];
    }
  }
  if (bid == 0 && tid == 0) {
    out[NN*3]     = sScal[2];  // counter (as float)
    out[NN*3 + 1] = sScal[1];  // fprob
  }
}

extern "C" void kernel_launch(void* const* d_in, const int* in_sizes, int n_in,
                              void* d_out, int out_size, void* d_ws, size_t ws_size,
                              hipStream_t stream) {
  const float* feat  = (const float*)d_in[0];
  const int*   src   = (const int*)d_in[1];
  const int*   dst   = (const int*)d_in[2];
  const float* W1    = (const float*)d_in[3];
  const float* b1    = (const float*)d_in[4];
  const float* W2    = (const float*)d_in[5];
  const float* b2    = (const float*)d_in[6];
  const float* W3    = (const float*)d_in[7];
  const float* b3    = (const float*)d_in[8];
  const float* W5    = (const float*)d_in[9];
  const float* b5    = (const float*)d_in[10];
  const float* wi    = (const float*)d_in[11];
  const float* wh    = (const float*)d_in[12];
  const float* bi    = (const float*)d_in[13];
  const float* bh    = (const float*)d_in[14];
  const float* w_end = (const float*)d_in[15];
  const float* b_end = (const float*)d_in[16];
  const int*   capp  = (const int*)d_in[17];

  float* out = (float*)d_out;
  char* wsb = (char*)d_ws;
  Ctrl*  ctrl   = (Ctrl*)wsb;
  float* x0g    = (float*)(wsb + 2048);
  float* x1g    = x0g + (size_t)(NN+1)*HD;
  float* ypub   = x1g + (size_t)(NN+1)*HD;
  float* gxpub  = ypub + (NN+1);

  lastgcn_kernel<<<dim3(NBLK), dim3(NTHR), 0, stream>>>(
      feat, src, dst, W1, b1, W2, b2, W3, b3, W5, b5,
      wi, wh, bi, bh, w_end, b_end, capp, out,
      ctrl, x0g, x1g, ypub, gxpub);
}

// Round 9
// 163.330 us; speedup vs baseline: 3.3667x; 1.0306x over previous
//
#include <hip/hip_runtime.h>
#include <math.h>

#define NN 588
#define EE 9408
#define HD 64
#define NBLK 8
#define NTHR 1024
#define NWAVE (NTHR/64)   // 16
#define GXROWS (192/NBLK) // 24
#define NEGS 0.01f
#define THRESHV 0.999f
#define MAGIC 0x51CAFE17u
#define DROW NN
#define EPADCAP 13536     // >= 9408 + 588*7

struct Ctrl {
  unsigned ready;  unsigned pad0[15];
  unsigned gen;    unsigned pad1[15];
  unsigned flags[NBLK*16];   // one 64B line per block
};

__device__ __forceinline__ float lrelu(float v){ return v >= 0.f ? v : NEGS*v; }
__device__ __forceinline__ float sigm(float v){ return 1.f/(1.f+expf(-v)); }
__device__ __forceinline__ float rdlane(float v, int l){
  return __int_as_float(__builtin_amdgcn_readlane(__float_as_int(v), l));
}
__device__ __forceinline__ float wredsum(float v){
  v += __shfl_down(v,32); v += __shfl_down(v,16); v += __shfl_down(v,8);
  v += __shfl_down(v,4);  v += __shfl_down(v,2);  v += __shfl_down(v,1);
  return v;  // valid on lane 0
}
__device__ __forceinline__ void sink4(float4 v){
  asm volatile("" :: "v"(v.x), "v"(v.y), "v"(v.z), "v"(v.w));
}
__device__ __forceinline__ void prefetch_region(const float* p0, int nfloats, int t, int T){
  const float4* p = (const float4*)p0;
  const int n = nfloats >> 2;
  for (int base = t; base < n; base += T*8) {
    float4 v[8];
    #pragma unroll
    for (int u = 0; u < 8; ++u) { int i = base + u*T; if (i >= n) i = n - 1; v[u] = p[i]; }
    #pragma unroll
    for (int u = 0; u < 8; ++u) sink4(v[u]);
  }
}

// Flag-tree grid barrier: parallel per-block flag stores; block 0 polls + releases.
__device__ __forceinline__ void gbar(Ctrl* c, unsigned& mygen, int bid) {
  __syncthreads();
  ++mygen;
  if (bid == 0) {
    if ((threadIdx.x >> 6) == 0) {
      int lane = threadIdx.x & 63;
      const unsigned* fp = &c->flags[(lane+1)*16];
      long bail = 0;
      for (;;) {
        int ok = (lane >= NBLK-1) ? 1 :
                 (__hip_atomic_load(fp, __ATOMIC_RELAXED, __HIP_MEMORY_SCOPE_AGENT) >= mygen);
        if (__all(ok)) break;
        __builtin_amdgcn_s_sleep(1);
        if (++bail > (1L<<22)) break;
      }
      if (lane == 0) {
        __threadfence();   // flush own writes + invalidate before release
        __hip_atomic_store(&c->gen, mygen, __ATOMIC_RELEASE, __HIP_MEMORY_SCOPE_AGENT);
      }
    }
  } else if (threadIdx.x == 0) {
    __threadfence();       // release: my data visible before flag
    __hip_atomic_store(&c->flags[bid*16], mygen, __ATOMIC_RELEASE, __HIP_MEMORY_SCOPE_AGENT);
    long bail = 0;
    while (__hip_atomic_load(&c->gen, __ATOMIC_RELAXED, __HIP_MEMORY_SCOPE_AGENT) < mygen) {
      __builtin_amdgcn_s_sleep(1);
      if (++bail > (1L<<22)) break;
    }
    __threadfence();       // acquire: invalidate so fresh data is read
  }
  __syncthreads();
}

__global__ __launch_bounds__(NTHR)
void lastgcn_kernel(const float* __restrict__ feat, const int* __restrict__ src,
                    const int* __restrict__ dst,
                    const float* __restrict__ W1, const float* __restrict__ b1,
                    const float* __restrict__ W2, const float* __restrict__ b2,
                    const float* __restrict__ W3, const float* __restrict__ b3,
                    const float* __restrict__ W5, const float* __restrict__ b5,
                    const float* __restrict__ wi, const float* __restrict__ wh,
                    const float* __restrict__ bi, const float* __restrict__ bh,
                    const float* __restrict__ w_end, const float* __restrict__ b_end,
                    const int* __restrict__ capp,
                    float* __restrict__ out, Ctrl* ctrl,
                    float* __restrict__ x0g, float* __restrict__ x1g,
                    float* __restrict__ ypub, float* __restrict__ gxpub,
                    float* __restrict__ ghpub) {
  const int tid  = threadIdx.x;
  const int lane = tid & 63;
  const int w    = tid >> 6;
  const int bid  = blockIdx.x;
  const int nbeg = (NN*bid)/NBLK;
  const int nend = (NN*(bid+1))/NBLK;
  const int cnt  = nend - nbeg;          // 73 or 74
  const int r0   = bid*GXROWS;

  __shared__ float  W2L[64*64];             // 16384 B
  __shared__ unsigned short eidxL[EPADCAP]; // 27072 B
  __shared__ int    offL[NN+1];
  __shared__ int    curL[NN];
  __shared__ unsigned short degU[NN];
  __shared__ float  yF[NN+1];
  __shared__ float  inpF[NN];
  __shared__ float  stateL[64];
  __shared__ float4 f4L[80];
  __shared__ int    wsumL[NWAVE];
  __shared__ float  sScal[3];
  __shared__ int    sStop;
  unsigned mygen = 0;

  // ---- init gate ----
  if (bid == 0) {
    if (tid < HD) { x0g[DROW*HD + tid] = 0.f; x1g[DROW*HD + tid] = 0.f; }
    if (tid == 64) ypub[NN] = 0.f;
    if (tid >= 128 && tid < 128 + 16 + NBLK*16) {
      // zero gen line + flags region (words 16 .. 16+16+NBLK*16)
      ((unsigned*)ctrl)[tid - 128 + 16] = 0u;
    }
    __syncthreads();
    if (tid == 0) {
      __threadfence();
      __hip_atomic_store(&ctrl->ready, MAGIC, __ATOMIC_RELEASE, __HIP_MEMORY_SCOPE_AGENT);
    }
  } else if (tid == 0) {
    long bail = 0;
    while (__hip_atomic_load(&ctrl->ready, __ATOMIC_RELAXED, __HIP_MEMORY_SCOPE_AGENT) != MAGIC) {
      __builtin_amdgcn_s_sleep(1);
      if (++bail > (1L<<24)) break;
    }
    __threadfence();
  }
  __syncthreads();

  // ---- CSR build: waves 0-7 count degrees; waves 8-15 prefetch wi/wh rows ----
  for (int i = tid; i < NN; i += NTHR) curL[i] = 0;
  for (int i = tid; i < 1024; i += NTHR) ((float4*)W2L)[i] = ((const float4*)W2)[i];
  __syncthreads();
  if (w < 8) {
    for (int e = tid; e < EE; e += 512) atomicAdd(&curL[dst[e]], 1);
  } else {
    const int pt = tid - 512, PT = 512;
    prefetch_region(wi + r0*NN, GXROWS*NN, pt, PT);   // my 24 rows (56 KB)
    prefetch_region(wh + r0*64, GXROWS*64, pt, PT);   // my 24 gh rows (6 KB)
    prefetch_region(w_end, 64, pt, PT);
  }
  __syncthreads();

  // ---- padded exclusive scan (wave-level, 2 stages) ----
  {
    const int n0 = 2*tid, n1 = n0 + 1;
    int d0 = (n0 < NN) ? curL[n0] : 0;
    int d1 = (n1 < NN) ? curL[n1] : 0;
    int p0 = (d0 + 7) & ~7, p1 = (d1 + 7) & ~7;
    int my = p0 + p1;
    int inc = my;
    for (int o = 1; o < 64; o <<= 1) { int u = __shfl_up(inc, o); if (lane >= o) inc += u; }
    if (lane == 63) wsumL[w] = inc;
    __syncthreads();
    if (w == 0 && lane < NWAVE) {
      int s0 = wsumL[lane];
      int is = s0;
      for (int o = 1; o < NWAVE; o <<= 1) { int u = __shfl_up(is, o); if (lane >= o) is += u; }
      wsumL[lane] = is - s0;   // exclusive
    }
    __syncthreads();
    int base = wsumL[w] + inc - my;
    if (n0 < NN) { offL[n0] = base;      curL[n0] = base;      degU[n0] = (unsigned short)d0; }
    if (n1 < NN) { offL[n1] = base + p0; curL[n1] = base + p0; degU[n1] = (unsigned short)d1; }
    if (tid == NTHR-1) offL[NN] = base + p0 + p1;
  }
  __syncthreads();
  for (int e = tid; e < EE; e += NTHR) {
    int p = atomicAdd(&curL[dst[e]], 1);   // dst L2-warm from count sweep
    eidxL[p] = (unsigned short)src[e];
  }
  __syncthreads();
  {
    const int n0 = 2*tid, n1 = n0 + 1;
    if (n0 < NN) for (int k = curL[n0]; k < offL[n0+1]; ++k) eidxL[k] = (unsigned short)DROW;
    if (n1 < NN) for (int k = curL[n1]; k < offL[n1+1]; ++k) eidxL[k] = (unsigned short)DROW;
  }
  __syncthreads();

  // ---- conv1 on my partition (uint4 index unpack, masked loads) ----
  if (tid < cnt) {
    int n = nbeg + tid;
    int o = offL[n], o1 = offL[n+1];
    float fx=0.f, fy=0.f, fz=0.f, fw2=0.f;
    for (int k = o; k < o1; k += 8) {
      uint4 q = *(const uint4*)(eidxL + k);
      int id[8] = { (int)(q.x & 0xFFFF), (int)(q.x >> 16), (int)(q.y & 0xFFFF), (int)(q.y >> 16),
                    (int)(q.z & 0xFFFF), (int)(q.z >> 16), (int)(q.w & 0xFFFF), (int)(q.w >> 16) };
      float4 tv[8]; float m[8];
      #pragma unroll
      for (int u = 0; u < 8; ++u) {
        int valid = id[u] < NN;
        m[u] = valid ? 1.f : 0.f;
        tv[u] = *(const float4*)(feat + (valid ? id[u] : 0)*4);
      }
      #pragma unroll
      for (int u = 0; u < 8; ++u) { fx += m[u]*tv[u].x; fy += m[u]*tv[u].y; fz += m[u]*tv[u].z; fw2 += m[u]*tv[u].w; }
    }
    f4L[tid] = make_float4(fx, fy, fz, fw2);
  }
  __syncthreads();
  const float W3r = W3[lane];
  for (int i = w; i < cnt; i += NWAVE) {
    int n = nbeg + i; float4 f = f4L[i];
    float v = b1[lane] + f.x*W1[lane] + f.y*W1[64+lane] + f.z*W1[128+lane] + f.w*W1[192+lane];
    v = lrelu(v);
    x0g[n*HD + lane] = v;
    float yv = wredsum(v * W3r);
    if (lane == 0) ypub[n] = yv;
  }
  gbar(ctrl, mygen, bid);                // B1: x0 + y0 visible

  const float b3v = b3[0];

  // inp (ALL nodes, LDS) then my 24 gx rows -> publish -> barrier
  auto inp_gx = [&]() {
    for (int i = tid; i <= NN; i += NTHR) yF[i] = ypub[i];
    __syncthreads();
    for (int n = tid; n < NN; n += NTHR) {
      int o = offL[n], o1 = offL[n+1];
      float a = 0.f;
      for (int k = o; k < o1; k += 8) {
        uint4 q = *(const uint4*)(eidxL + k);
        a += yF[q.x & 0xFFFF] + yF[q.x >> 16] + yF[q.y & 0xFFFF] + yF[q.y >> 16];
        a += yF[q.z & 0xFFFF] + yF[q.z >> 16] + yF[q.w & 0xFFFF] + yF[q.w >> 16];
      }
      inpF[n] = lrelu(a + b3v);
    }
    __syncthreads();
    const float4* inp4 = (const float4*)inpF;   // 147 float4s
    for (int rr = w; rr < GXROWS; rr += NWAVE) {
      const float4* row4 = (const float4*)(wi + (r0 + rr)*NN);
      float p = 0.f;
      #pragma unroll
      for (int k = 0; k < 3; ++k) {
        int c = lane + (k << 6);
        if (c < 147) {
          float4 a = row4[c], b = inp4[c];
          p += a.x*b.x + a.y*b.y + a.z*b.z + a.w*b.w;
        }
      }
      p = wredsum(p);
      if (lane == 0) gxpub[r0 + rr] = p + bi[r0 + rr];
    }
    gbar(ctrl, mygen, bid);              // B_gx
  };

  inp_gx();

  // ---- GRU init, replicated in every block ----
  if (w == 0) {
    int j = lane;
    float r  = sigm(gxpub[j]      + bh[j]);
    float z  = sigm(gxpub[64+j]   + bh[64+j]);
    float n2 = tanhf(gxpub[128+j] + r*bh[128+j]);
    float st = (1.f - z)*n2;             // h0 = 0
    stateL[j] = st;
    float t2 = wredsum(st * w_end[j]);
    if (j == 0) {
      float pr = sigm(t2 + b_end[0]);
      sScal[0] = pr; sScal[1] = pr; sScal[2] = 0.f;
      sStop = (pr >= THRESHV) ? 1 : 0;
    }
  }
  __syncthreads();
  // gh distributed: my 24 rows published; visible to all by B_a of iter0.
  for (int rr = w; rr < GXROWS; rr += NWAVE) {
    int r = r0 + rr;
    float p = wredsum(wh[r*64 + lane] * stateL[lane]);
    if (lane == 0) ghpub[r] = p + bh[r];
  }
  __syncthreads();

  // ---- main loop ----
  const int cap = capp[0];
  float* xc = x0g;
  float* xn = x1g;
  const float b2r = b2[lane];
  for (int it = 0; it < cap; ++it) {
    if (sStop) break;                    // uniform (replicated GRU)

    // conv2: node pairs per wave; wave-uniform uint4 index broadcast
    for (int i = w; i < cnt; i += 2*NWAVE) {
      int i2 = i + NWAVE;
      bool has2 = (i2 < cnt);
      int nA = nbeg + i, nB = nbeg + (has2 ? i2 : i);
      int oA = offL[nA], lA = offL[nA+1] - oA;
      int oB = offL[nB], lB = offL[nB+1] - oB;
      float accA = 0.f, accB = 0.f;
      int pcm = lA > lB ? lA : lB;
      for (int k = 0; k < pcm; k += 8) {
        float ta[8], tb[8];
        if (k < lA) {
          uint4 q = *(const uint4*)(eidxL + oA + k);
          ta[0] = xc[(int)(q.x & 0xFFFF)*HD + lane]; ta[1] = xc[(int)(q.x >> 16)*HD + lane];
          ta[2] = xc[(int)(q.y & 0xFFFF)*HD + lane]; ta[3] = xc[(int)(q.y >> 16)*HD + lane];
          ta[4] = xc[(int)(q.z & 0xFFFF)*HD + lane]; ta[5] = xc[(int)(q.z >> 16)*HD + lane];
          ta[6] = xc[(int)(q.w & 0xFFFF)*HD + lane]; ta[7] = xc[(int)(q.w >> 16)*HD + lane];
        } else { for (int u = 0; u < 8; ++u) ta[u] = 0.f; }
        if (k < lB) {
          uint4 q = *(const uint4*)(eidxL + oB + k);
          tb[0] = xc[(int)(q.x & 0xFFFF)*HD + lane]; tb[1] = xc[(int)(q.x >> 16)*HD + lane];
          tb[2] = xc[(int)(q.y & 0xFFFF)*HD + lane]; tb[3] = xc[(int)(q.y >> 16)*HD + lane];
          tb[4] = xc[(int)(q.z & 0xFFFF)*HD + lane]; tb[5] = xc[(int)(q.z >> 16)*HD + lane];
          tb[6] = xc[(int)(q.w & 0xFFFF)*HD + lane]; tb[7] = xc[(int)(q.w >> 16)*HD + lane];
        } else { for (int u = 0; u < 8; ++u) tb[u] = 0.f; }
        #pragma unroll
        for (int u = 0; u < 8; ++u) { accA += ta[u]; accB += tb[u]; }
      }
      float a0=0.f,a1=0.f,a2=0.f,a3=0.f, c0=0.f,c1=0.f,c2=0.f,c3=0.f;
      #pragma unroll
      for (int l = 0; l < 64; l += 4) {
        float w0 = W2L[(l+0)*64 + lane];
        float w1v = W2L[(l+1)*64 + lane];
        float w2v = W2L[(l+2)*64 + lane];
        float w3v = W2L[(l+3)*64 + lane];
        a0 = fmaf(rdlane(accA,l+0), w0,  a0);  c0 = fmaf(rdlane(accB,l+0), w0,  c0);
        a1 = fmaf(rdlane(accA,l+1), w1v, a1);  c1 = fmaf(rdlane(accB,l+1), w1v, c1);
        a2 = fmaf(rdlane(accA,l+2), w2v, a2);  c2 = fmaf(rdlane(accB,l+2), w2v, c2);
        a3 = fmaf(rdlane(accA,l+3), w3v, a3);  c3 = fmaf(rdlane(accB,l+3), w3v, c3);
      }
      {
        float vA = lrelu(b2r + (a0+a1)+(a2+a3));
        xn[nA*HD + lane] = vA;
        float yv = wredsum(vA * W3r);
        if (lane == 0) ypub[nA] = yv;
      }
      if (has2) {
        float vB = lrelu(b2r + (c0+c1)+(c2+c3));
        xn[nB*HD + lane] = vB;
        float yv = wredsum(vB * W3r);
        if (lane == 0) ypub[nB] = yv;
      }
    }
    gbar(ctrl, mygen, bid);              // B_a: xn + y (+ghpub from init) visible

    inp_gx();                            // inp + gx + B_gx

    if (w == 0) {                        // GRU tail, replicated; gh/gx from global
      int j = lane;
      float r  = sigm(gxpub[j]      + ghpub[j]);
      float z  = sigm(gxpub[64+j]   + ghpub[64+j]);
      float n2 = tanhf(gxpub[128+j] + r*ghpub[128+j]);
      float st = (1.f - z)*n2 + z*stateL[j];   // frozen state
      float t2 = wredsum(st * w_end[j]);
      if (j == 0) {
        float pr = sigm(t2 + b_end[0]);
        float s = sScal[0] + pr;
        sScal[0] = s; sScal[1] = pr; sScal[2] += 1.f;
        sStop = (s >= THRESHV) ? 1 : 0;
      }
    }
    __syncthreads();
    { float* t = xc; xc = xn; xn = t; }
  }

  // ---- final conv on my partition ----
  for (int i = w; i < cnt; i += NWAVE) {
    int n = nbeg + i;
    int o = offL[n], o1 = offL[n+1];
    float acc = 0.f;
    for (int k = o; k < o1; k += 8) {
      uint4 q = *(const uint4*)(eidxL + k);
      float t[8];
      t[0] = xc[(int)(q.x & 0xFFFF)*HD + lane]; t[1] = xc[(int)(q.x >> 16)*HD + lane];
      t[2] = xc[(int)(q.y & 0xFFFF)*HD + lane]; t[3] = xc[(int)(q.y >> 16)*HD + lane];
      t[4] = xc[(int)(q.z & 0xFFFF)*HD + lane]; t[5] = xc[(int)(q.z >> 16)*HD + lane];
      t[6] = xc[(int)(q.w & 0xFFFF)*HD + lane]; t[7] = xc[(int)(q.w >> 16)*HD + lane];
      #pragma unroll
      for (int u = 0; u < 8; ++u) acc += t[u];
    }
    float p0 = wredsum(acc * W5[lane*3 + 0]);
    float p1 = wredsum(acc * W5[lane*3 + 1]);
    float p2 = wredsum(acc * W5[lane*3 + 2]);
    if (lane == 0) {
      out[n*3 + 0] = p0 + b5[0];
      out[n*3 + 1] = p1 + b5[1];
      out[n*3 + 2] = p2 + b5[2];
    }
  }
  if (bid == 0 && tid == 0) {
    out[NN*3]     = sScal[2];  // counter (as float)
    out[NN*3 + 1] = sScal[1];  // fprob
  }
}

extern "C" void kernel_launch(void* const* d_in, const int* in_sizes, int n_in,
                              void* d_out, int out_size, void* d_ws, size_t ws_size,
                              hipStream_t stream) {
  const float* feat  = (const float*)d_in[0];
  const int*   src   = (const int*)d_in[1];
  const int*   dst   = (const int*)d_in[2];
  const float* W1    = (const float*)d_in[3];
  const float* b1    = (const float*)d_in[4];
  const float* W2    = (const float*)d_in[5];
  const float* b2    = (const float*)d_in[6];
  const float* W3    = (const float*)d_in[7];
  const float* b3    = (const float*)d_in[8];
  const float* W5    = (const float*)d_in[9];
  const float* b5    = (const float*)d_in[10];
  const float* wi    = (const float*)d_in[11];
  const float* wh    = (const float*)d_in[12];
  const float* bi    = (const float*)d_in[13];
  const float* bh    = (const float*)d_in[14];
  const float* w_end = (const float*)d_in[15];
  const float* b_end = (const float*)d_in[16];
  const int*   capp  = (const int*)d_in[17];

  float* out = (float*)d_out;
  char* wsb = (char*)d_ws;
  Ctrl*  ctrl   = (Ctrl*)wsb;
  float* x0g    = (float*)(wsb + 2048);
  float* x1g    = x0g + (size_t)(NN+1)*HD;
  float* ypub   = x1g + (size_t)(NN+1)*HD;
  float* gxpub  = ypub + (NN+1);
  float* ghpub  = gxpub + 192;

  lastgcn_kernel<<<dim3(NBLK), dim3(NTHR), 0, stream>>>(
      feat, src, dst, W1, b1, W2, b2, W3, b3, W5, b5,
      wi, wh, bi, bh, w_end, b_end, capp, out,
      ctrl, x0g, x1g, ypub, gxpub, ghpub);
}